// Round 1
// baseline (1964.307 us; speedup 1.0000x reference)
//
#include <hip/hip_runtime.h>

#define BATCH 8
#define NPTS 2048
#define KNNK 16
#define CH 64
#define CF 128
#define CA 256
#define CB 512
#define CCAT 640
#define CC 256
#define CD 128
#define CE 256
#define CG 512
#define NGRP 4
#define GSZ 32
#define EPSF 1e-5f
#define GF_OFF (BATCH*CG)
#define TN 8

#define FMA4(acc, base, vec, s) \
  acc[base+0] += vec.x*(s); acc[base+1] += vec.y*(s); \
  acc[base+2] += vec.z*(s); acc[base+3] += vec.w*(s);

// dst[c*R + r] = src[r*C + c]
__global__ void k_transpose(const float* __restrict__ src, float* __restrict__ dst,
                            int R, int C) {
  int i = blockIdx.x * 256 + threadIdx.x;
  if (i < R * C) {
    int r = i / C, c = i - r * C;
    dst[c * R + r] = src[i];
  }
}

__global__ void k_sq_h(const float* __restrict__ x, const float* __restrict__ f,
                       const float* __restrict__ Wit, const float* __restrict__ bit,
                       float* __restrict__ sq, float* __restrict__ h) {
  int t = blockIdx.x * 256 + threadIdx.x;
  if (t >= BATCH * NPTS * CH) return;
  int o = t & (CH - 1);
  int bn = t >> 6;
  int n = bn & (NPTS - 1);
  int b = bn >> 11;
  float f0 = f[(b*3 + 0)*NPTS + n];
  float f1 = f[(b*3 + 1)*NPTS + n];
  float f2 = f[(b*3 + 2)*NPTS + n];
  h[t] = f0*Wit[o*3+0] + f1*Wit[o*3+1] + f2*Wit[o*3+2] + bit[o];
  if (o == 0) {
    float x0 = x[(b*3 + 0)*NPTS + n];
    float x1 = x[(b*3 + 1)*NPTS + n];
    float x2 = x[(b*3 + 2)*NPTS + n];
    // match numpy rounding: ((x0*x0 + x1*x1) + x2*x2), no FMA contraction
    sq[bn] = __fadd_rn(__fadd_rn(__fmul_rn(x0,x0), __fmul_rn(x1,x1)), __fmul_rn(x2,x2));
  }
}

__global__ void k_knn(const float* __restrict__ x, const float* __restrict__ sq,
                      int* __restrict__ idxout) {
  __shared__ float dist[NPTS];
  __shared__ float rv[256];
  __shared__ int ri[256];
  int bn = blockIdx.x;
  int b = bn >> 11;
  int n = bn & (NPTS - 1);
  int t = threadIdx.x;
  float qx = x[(b*3+0)*NPTS + n];
  float qy = x[(b*3+1)*NPTS + n];
  float qz = x[(b*3+2)*NPTS + n];
  float sqq = sq[bn];
  for (int m = t; m < NPTS; m += 256) {
    float mx = x[(b*3+0)*NPTS + m];
    float my = x[(b*3+1)*NPTS + m];
    float mz = x[(b*3+2)*NPTS + m];
    // d = (sq_n + sq_m) - 2*dot, each op rounded exactly as numpy does
    float dot = __fadd_rn(__fadd_rn(__fmul_rn(qx,mx), __fmul_rn(qy,my)), __fmul_rn(qz,mz));
    dist[m] = __fsub_rn(__fadd_rn(sqq, sq[b*NPTS+m]), __fadd_rn(dot,dot));
  }
  __syncthreads();
  for (int k = 0; k < KNNK; ++k) {
    float bv = 3.0e38f; int bi = 0x7fffffff;
    for (int m = t; m < NPTS; m += 256) {
      float v = dist[m];
      if (v < bv || (v == bv && m < bi)) { bv = v; bi = m; }
    }
    rv[t] = bv; ri[t] = bi;
    __syncthreads();
    for (int s = 128; s > 0; s >>= 1) {
      if (t < s) {
        float v2 = rv[t+s]; int i2 = ri[t+s];
        if (v2 < rv[t] || (v2 == rv[t] && i2 < ri[t])) { rv[t] = v2; ri[t] = i2; }
      }
      __syncthreads();
    }
    if (t == 0) {
      idxout[bn*KNNK + k] = ri[0];
      dist[ri[0]] = 3.0e38f;
    }
    __syncthreads();
  }
}

__global__ __launch_bounds__(256)
void k_stats(const float* __restrict__ h, const int* __restrict__ idx,
             const float* __restrict__ W1T, float* __restrict__ partials) {
  __shared__ float featT[CF][20];
  __shared__ float red[256];
  __shared__ float gsum[NGRP];
  int bn = blockIdx.x;
  int b = bn >> 11;
  int t = threadIdx.x;
  {
    int c = t & 63;
    float hq = h[(size_t)bn*CH + c];
    for (int k = t >> 6; k < KNNK; k += 4) {
      int nb = idx[bn*KNNK + k];
      float hv = h[((size_t)b*NPTS + nb)*CH + c];
      featT[c][k] = hv - hq;
      featT[c+64][k] = hq;
    }
  }
  __syncthreads();
  int o = t & 127, kh = t >> 7;
  float acc[8];
#pragma unroll
  for (int j = 0; j < 8; ++j) acc[j] = 0.f;
  for (int c = 0; c < CF; ++c) {
    float wv = W1T[c*CF + o];
    const float4* fp = (const float4*)&featT[c][kh*8];
    float4 f0 = fp[0], f1 = fp[1];
    FMA4(acc, 0, f0, wv)
    FMA4(acc, 4, f1, wv)
  }
  float s = 0.f, ss = 0.f;
#pragma unroll
  for (int j = 0; j < 8; ++j) { s += acc[j]; ss += acc[j]*acc[j]; }
  red[t] = s;
  __syncthreads();
  if (t < NGRP) {
    float a = 0.f;
    for (int o2 = t*GSZ; o2 < (t+1)*GSZ; ++o2) a += red[o2] + red[o2+128];
    gsum[t] = a;
  }
  __syncthreads();
  red[t] = ss;
  __syncthreads();
  if (t < NGRP) {
    float a = 0.f;
    for (int o2 = t*GSZ; o2 < (t+1)*GSZ; ++o2) a += red[o2] + red[o2+128];
    partials[(size_t)bn*NGRP*2 + t*2 + 0] = gsum[t];
    partials[(size_t)bn*NGRP*2 + t*2 + 1] = a;
  }
}

__global__ void k_reduce(const float* __restrict__ partials, float* __restrict__ stats) {
  int b = blockIdx.x >> 2;
  int g = blockIdx.x & 3;
  int t = threadIdx.x;
  float s = 0.f, ss = 0.f;
  for (int n = t; n < NPTS; n += 256) {
    const float* p = &partials[((size_t)(b*NPTS + n)*NGRP + g)*2];
    s += p[0]; ss += p[1];
  }
  __shared__ float rs[256], rss[256];
  rs[t] = s; rss[t] = ss;
  __syncthreads();
  for (int st = 128; st > 0; st >>= 1) {
    if (t < st) { rs[t] += rs[t+st]; rss[t] += rss[t+st]; }
    __syncthreads();
  }
  if (t == 0) {
    const float cnt = (float)(NPTS*KNNK*GSZ);
    float mu = rs[0] / cnt;
    float var = rss[0] / cnt - mu*mu;
    stats[(b*NGRP+g)*2+0] = mu;
    stats[(b*NGRP+g)*2+1] = rsqrtf(var + EPSF);
  }
}

__global__ __launch_bounds__(256)
void k_main(const float* __restrict__ h, const int* __restrict__ idx,
            const float* __restrict__ W1T, const float* __restrict__ gng,
            const float* __restrict__ gnb, const float* __restrict__ stats,
            const float* __restrict__ WaT, const float* __restrict__ ba,
            const float* __restrict__ WbT, const float* __restrict__ bb,
            float* __restrict__ lbase, unsigned* __restrict__ gmaxU) {
  __shared__ float featT[CF][20];
  __shared__ float ynT[CF][20];
  __shared__ float g1T[CA][20];
  int bn = blockIdx.x;
  int b = bn >> 11;
  int t = threadIdx.x;
  {
    int c = t & 63;
    float hq = h[(size_t)bn*CH + c];
    for (int k = t >> 6; k < KNNK; k += 4) {
      int nb = idx[bn*KNNK + k];
      float hv = h[((size_t)b*NPTS + nb)*CH + c];
      featT[c][k] = hv - hq;
      featT[c+64][k] = hq;
    }
  }
  __syncthreads();
  // y = feat @ W1^T, then GroupNorm affine + leaky relu
  {
    int o = t & 127, kh = t >> 7;
    float acc[8];
#pragma unroll
    for (int j = 0; j < 8; ++j) acc[j] = 0.f;
    for (int c = 0; c < CF; ++c) {
      float wv = W1T[c*CF + o];
      const float4* fp = (const float4*)&featT[c][kh*8];
      float4 f0 = fp[0], f1 = fp[1];
      FMA4(acc, 0, f0, wv)
      FMA4(acc, 4, f1, wv)
    }
    int g = o >> 5;
    float mu = stats[(b*NGRP+g)*2+0];
    float rsg = stats[(b*NGRP+g)*2+1];
    float ga = gng[o], bev = gnb[o];
#pragma unroll
    for (int j = 0; j < 8; ++j) {
      float v = (acc[j]-mu)*rsg*ga + bev;
      v = (v >= 0.f) ? v : 0.2f*v;
      ynT[o][kh*8+j] = v;
    }
  }
  __syncthreads();
  if (t < CF) {
    float m = ynT[t][0];
#pragma unroll
    for (int k = 1; k < KNNK; ++k) m = fmaxf(m, ynT[t][k]);
    lbase[(size_t)bn*CF + t] = m;
  }
  // g1 = relu(yn @ Wa^T + ba), per-thread output channel t, all 16 k
  {
    float a1[16];
#pragma unroll
    for (int k = 0; k < 16; ++k) a1[k] = 0.f;
    for (int c = 0; c < CF; ++c) {
      float wv = WaT[c*CA + t];
      const float4* yp = (const float4*)&ynT[c][0];
      float4 y0 = yp[0], y1 = yp[1], y2 = yp[2], y3 = yp[3];
      FMA4(a1, 0, y0, wv)
      FMA4(a1, 4, y1, wv)
      FMA4(a1, 8, y2, wv)
      FMA4(a1, 12, y3, wv)
    }
    float bv = ba[t];
#pragma unroll
    for (int k = 0; k < 16; ++k) g1T[t][k] = fmaxf(a1[k]+bv, 0.f);
  }
  __syncthreads();
  // g2 = relu(g1 @ Wb^T + bb), fused max over k, atomic max over n
  {
    float a0[16], a1[16];
#pragma unroll
    for (int k = 0; k < 16; ++k) { a0[k] = 0.f; a1[k] = 0.f; }
    for (int c = 0; c < CA; ++c) {
      float w0 = WbT[c*CG + t];
      float w1 = WbT[c*CG + t + 256];
      const float4* gp = (const float4*)&g1T[c][0];
      float4 q0 = gp[0], q1 = gp[1], q2 = gp[2], q3 = gp[3];
      FMA4(a0, 0, q0, w0)
      FMA4(a0, 4, q1, w0)
      FMA4(a0, 8, q2, w0)
      FMA4(a0, 12, q3, w0)
      FMA4(a1, 0, q0, w1)
      FMA4(a1, 4, q1, w1)
      FMA4(a1, 8, q2, w1)
      FMA4(a1, 12, q3, w1)
    }
    float b0 = bb[t], b1 = bb[t+256];
    float m0 = 0.f, m1 = 0.f;   // relu folded into max with 0
#pragma unroll
    for (int k = 0; k < 16; ++k) { m0 = fmaxf(m0, a0[k]+b0); m1 = fmaxf(m1, a1[k]+b1); }
    atomicMax(&gmaxU[b*CG + t], __float_as_uint(m0));
    atomicMax(&gmaxU[b*CG + t + 256], __float_as_uint(m1));
  }
}

__global__ __launch_bounds__(256)
void k_tail(const float* __restrict__ lbase, const unsigned* __restrict__ gmaxU,
            const float* __restrict__ WcT, const float* __restrict__ bc,
            const float* __restrict__ WdT, const float* __restrict__ bd,
            const float* __restrict__ WeT, const float* __restrict__ be,
            const float* __restrict__ WfT, const float* __restrict__ bf,
            float* __restrict__ out, unsigned* __restrict__ glmaxU) {
  __shared__ float cat[TN][CCAT];
  __shared__ float lf1s[TN][CC];
  __shared__ float lf2s[TN][CD];
  __shared__ float gl1s[TN][CE];
  int blk = blockIdx.x;
  int b = blk >> 8;            // 256 blocks per batch
  int n0 = (blk & 255) * TN;
  int t = threadIdx.x;
  for (int i = t; i < TN*CF; i += 256) {
    int nn = i >> 7, c = i & 127;
    cat[nn][c] = lbase[((size_t)(b*NPTS + n0 + nn))*CF + c];
  }
  for (int i = t; i < CB; i += 256) {
    float g = __uint_as_float(gmaxU[b*CB + i]);
#pragma unroll
    for (int nn = 0; nn < TN; ++nn) cat[nn][CF + i] = g;
  }
  __syncthreads();
  // lf1 = relu(cat @ Wc^T + bc)
  {
    float acc[TN];
#pragma unroll
    for (int nn = 0; nn < TN; ++nn) acc[nn] = 0.f;
    for (int c = 0; c < CCAT; ++c) {
      float wv = WcT[c*CC + t];
#pragma unroll
      for (int nn = 0; nn < TN; ++nn) acc[nn] += cat[nn][c]*wv;
    }
    float bv = bc[t];
#pragma unroll
    for (int nn = 0; nn < TN; ++nn) lf1s[nn][t] = fmaxf(acc[nn]+bv, 0.f);
  }
  __syncthreads();
  // lf2 = relu(lf1 @ Wd^T + bd) -> local_feat output (transposed)
  if (t < CD) {
    float acc[TN];
#pragma unroll
    for (int nn = 0; nn < TN; ++nn) acc[nn] = 0.f;
    for (int c = 0; c < CC; ++c) {
      float wv = WdT[c*CD + t];
#pragma unroll
      for (int nn = 0; nn < TN; ++nn) acc[nn] += lf1s[nn][c]*wv;
    }
    float bv = bd[t];
#pragma unroll
    for (int nn = 0; nn < TN; ++nn) {
      float v = fmaxf(acc[nn]+bv, 0.f);
      lf2s[nn][t] = v;
      out[GF_OFF + ((size_t)(b*CD + t))*NPTS + n0 + nn] = v;
    }
  }
  __syncthreads();
  // gl1 = relu(lf2 @ We^T + be)
  {
    float acc[TN];
#pragma unroll
    for (int nn = 0; nn < TN; ++nn) acc[nn] = 0.f;
    for (int c = 0; c < CD; ++c) {
      float wv = WeT[c*CE + t];
#pragma unroll
      for (int nn = 0; nn < TN; ++nn) acc[nn] += lf2s[nn][c]*wv;
    }
    float bv = be[t];
#pragma unroll
    for (int nn = 0; nn < TN; ++nn) gl1s[nn][t] = fmaxf(acc[nn]+bv, 0.f);
  }
  __syncthreads();
  // gl2 = relu(gl1 @ Wf^T + bf), max over nn, atomic max over n
  {
    float a0[TN], a1[TN];
#pragma unroll
    for (int nn = 0; nn < TN; ++nn) { a0[nn] = 0.f; a1[nn] = 0.f; }
    for (int c = 0; c < CE; ++c) {
      float w0 = WfT[c*CG + t];
      float w1 = WfT[c*CG + t + 256];
#pragma unroll
      for (int nn = 0; nn < TN; ++nn) {
        float v = gl1s[nn][c];
        a0[nn] += v*w0; a1[nn] += v*w1;
      }
    }
    float b0 = bf[t], b1 = bf[t+256];
    float m0 = 0.f, m1 = 0.f;
#pragma unroll
    for (int nn = 0; nn < TN; ++nn) { m0 = fmaxf(m0, a0[nn]+b0); m1 = fmaxf(m1, a1[nn]+b1); }
    atomicMax(&glmaxU[b*CG + t], __float_as_uint(m0));
    atomicMax(&glmaxU[b*CG + t + 256], __float_as_uint(m1));
  }
}

__global__ void k_final(const unsigned* __restrict__ glmaxU, float* __restrict__ out) {
  int i = blockIdx.x*256 + threadIdx.x;
  if (i < BATCH*CG) out[i] = __uint_as_float(glmaxU[i]);
}

extern "C" void kernel_launch(void* const* d_in, const int* in_sizes, int n_in,
                              void* d_out, int out_size, void* d_ws, size_t ws_size,
                              hipStream_t stream) {
  const float* x   = (const float*)d_in[0];
  const float* f   = (const float*)d_in[1];
  const float* Wit = (const float*)d_in[2];
  const float* bit = (const float*)d_in[3];
  const float* W1  = (const float*)d_in[4];
  const float* gng = (const float*)d_in[5];
  const float* gnb = (const float*)d_in[6];
  const float* Wa  = (const float*)d_in[7];
  const float* ba  = (const float*)d_in[8];
  const float* Wb  = (const float*)d_in[9];
  const float* bb  = (const float*)d_in[10];
  const float* Wc  = (const float*)d_in[11];
  const float* bc  = (const float*)d_in[12];
  const float* Wd  = (const float*)d_in[13];
  const float* bd  = (const float*)d_in[14];
  const float* We  = (const float*)d_in[15];
  const float* be  = (const float*)d_in[16];
  const float* Wf  = (const float*)d_in[17];
  const float* bf  = (const float*)d_in[18];
  float* out = (float*)d_out;

  char* w = (char*)d_ws;
  size_t off = 0;
  auto alloc = [&](size_t bytes) {
    void* p = w + off; off += (bytes + 255) & ~(size_t)255; return p;
  };
  float* h        = (float*)alloc((size_t)BATCH*NPTS*CH*4);
  float* sq       = (float*)alloc((size_t)BATCH*NPTS*4);
  int*   idx      = (int*)  alloc((size_t)BATCH*NPTS*KNNK*4);
  float* W1T      = (float*)alloc((size_t)CF*CF*4);
  float* WaT      = (float*)alloc((size_t)CF*CA*4);
  float* WbT      = (float*)alloc((size_t)CA*CB*4);
  float* WcT      = (float*)alloc((size_t)CCAT*CC*4);
  float* WdT      = (float*)alloc((size_t)CC*CD*4);
  float* WeT      = (float*)alloc((size_t)CD*CE*4);
  float* WfT      = (float*)alloc((size_t)CE*CG*4);
  float* partials = (float*)alloc((size_t)BATCH*NPTS*NGRP*2*4);
  float* stats    = (float*)alloc((size_t)BATCH*NGRP*2*4);
  float* lbase    = (float*)alloc((size_t)BATCH*NPTS*CF*4);
  unsigned* gmaxU  = (unsigned*)alloc((size_t)BATCH*CG*4);
  unsigned* glmaxU = (unsigned*)alloc((size_t)BATCH*CG*4);

  hipMemsetAsync(gmaxU, 0, (size_t)BATCH*CG*4, stream);
  hipMemsetAsync(glmaxU, 0, (size_t)BATCH*CG*4, stream);

  k_transpose<<<(CF*CF+255)/256, 256, 0, stream>>>(W1, W1T, CF, CF);
  k_transpose<<<(CA*CF+255)/256, 256, 0, stream>>>(Wa, WaT, CA, CF);
  k_transpose<<<(CB*CA+255)/256, 256, 0, stream>>>(Wb, WbT, CB, CA);
  k_transpose<<<(CC*CCAT+255)/256, 256, 0, stream>>>(Wc, WcT, CC, CCAT);
  k_transpose<<<(CD*CC+255)/256, 256, 0, stream>>>(Wd, WdT, CD, CC);
  k_transpose<<<(CE*CD+255)/256, 256, 0, stream>>>(We, WeT, CE, CD);
  k_transpose<<<(CG*CE+255)/256, 256, 0, stream>>>(Wf, WfT, CG, CE);

  k_sq_h<<<(BATCH*NPTS*CH+255)/256, 256, 0, stream>>>(x, f, Wit, bit, sq, h);
  k_knn<<<BATCH*NPTS, 256, 0, stream>>>(x, sq, idx);
  k_stats<<<BATCH*NPTS, 256, 0, stream>>>(h, idx, W1T, partials);
  k_reduce<<<BATCH*NGRP, 256, 0, stream>>>(partials, stats);
  k_main<<<BATCH*NPTS, 256, 0, stream>>>(h, idx, W1T, gng, gnb, stats,
                                         WaT, ba, WbT, bb, lbase, gmaxU);
  k_tail<<<BATCH*NPTS/TN, 256, 0, stream>>>(lbase, gmaxU, WcT, bc, WdT, bd,
                                            WeT, be, WfT, bf, out, glmaxU);
  k_final<<<(BATCH*CG+255)/256, 256, 0, stream>>>(glmaxU, out);
}

// Round 2
// 805.099 us; speedup vs baseline: 2.4398x; 2.4398x over previous
//
#include <hip/hip_runtime.h>

#define BATCH 8
#define NPTS 2048
#define KNNK 16
#define CH 64
#define CF 128
#define CA 256
#define CB 512
#define CCAT 640
#define CC 256
#define CD 128
#define CE 256
#define CG 512
#define NGRP 4
#define EPSF 1e-5f
#define GF_OFF (BATCH*CG)
#define TN 8
#define P 8              // points per MFMA block
#define MROWS (P*KNNK)   // 128 rows

typedef __attribute__((ext_vector_type(8))) short short8v;
typedef __attribute__((ext_vector_type(4))) float f32x4;

__device__ inline short f2bf(float f) {
  union { float f; unsigned u; } v; v.f = f;
  unsigned r = v.u + 0x7fff + ((v.u >> 16) & 1);
  return (short)(r >> 16);
}

// XOR-swizzled LDS element index (bf16 elements; flips 16B slot within 128B)
#define LIDX(r, c, ROW) ((r)*(ROW) + ((c) ^ (((r)&7)<<3)))

// dst[c*R + r] = src[r*C + c]
__global__ void k_transpose(const float* __restrict__ src, float* __restrict__ dst,
                            int R, int C) {
  int i = blockIdx.x * 256 + threadIdx.x;
  if (i < R * C) {
    int r = i / C, c = i - r * C;
    dst[c * R + r] = src[i];
  }
}

// pack W[O][C] (f32) into MFMA B-fragment-linear bf16:
// Wp[((nt*KS+ks)*64 + lane)*8 + j] = bf16(W[nt*16+(lane&15)][ks*32+(lane>>4)*8+j])
__global__ void k_pack(const float* __restrict__ W, short* __restrict__ Wp,
                       int O, int C) {
  int tid = blockIdx.x * 256 + threadIdx.x;
  int KS = C >> 5;
  int total = (O >> 4) * KS * 64;
  if (tid >= total) return;
  int l = tid & 63;
  int fs = tid >> 6;
  int nt = fs / KS, ks = fs - nt * KS;
  int o = nt * 16 + (l & 15);
  int c = ks * 32 + (l >> 4) * 8;
  const float* src = W + (size_t)o * C + c;
  short8v v;
#pragma unroll
  for (int j = 0; j < 8; ++j) v[j] = f2bf(src[j]);
  *(short8v*)&Wp[(size_t)tid * 8] = v;
}

__global__ void k_sq_h(const float* __restrict__ x, const float* __restrict__ f,
                       const float* __restrict__ Wit, const float* __restrict__ bit,
                       float* __restrict__ sq, float* __restrict__ h) {
  int t = blockIdx.x * 256 + threadIdx.x;
  if (t >= BATCH * NPTS * CH) return;
  int o = t & (CH - 1);
  int bn = t >> 6;
  int n = bn & (NPTS - 1);
  int b = bn >> 11;
  float f0 = f[(b*3 + 0)*NPTS + n];
  float f1 = f[(b*3 + 1)*NPTS + n];
  float f2 = f[(b*3 + 2)*NPTS + n];
  h[t] = f0*Wit[o*3+0] + f1*Wit[o*3+1] + f2*Wit[o*3+2] + bit[o];
  if (o == 0) {
    float x0 = x[(b*3 + 0)*NPTS + n];
    float x1 = x[(b*3 + 1)*NPTS + n];
    float x2 = x[(b*3 + 2)*NPTS + n];
    sq[bn] = __fadd_rn(__fadd_rn(__fmul_rn(x0,x0), __fmul_rn(x1,x1)), __fmul_rn(x2,x2));
  }
}

__global__ void k_knn(const float* __restrict__ x, const float* __restrict__ sq,
                      int* __restrict__ idxout) {
  __shared__ float dist[NPTS];
  __shared__ float rv[256];
  __shared__ int ri[256];
  int bn = blockIdx.x;
  int b = bn >> 11;
  int n = bn & (NPTS - 1);
  int t = threadIdx.x;
  float qx = x[(b*3+0)*NPTS + n];
  float qy = x[(b*3+1)*NPTS + n];
  float qz = x[(b*3+2)*NPTS + n];
  float sqq = sq[bn];
  for (int m = t; m < NPTS; m += 256) {
    float mx = x[(b*3+0)*NPTS + m];
    float my = x[(b*3+1)*NPTS + m];
    float mz = x[(b*3+2)*NPTS + m];
    float dot = __fadd_rn(__fadd_rn(__fmul_rn(qx,mx), __fmul_rn(qy,my)), __fmul_rn(qz,mz));
    dist[m] = __fsub_rn(__fadd_rn(sqq, sq[b*NPTS+m]), __fadd_rn(dot,dot));
  }
  __syncthreads();
  for (int k = 0; k < KNNK; ++k) {
    float bv = 3.0e38f; int bi = 0x7fffffff;
    for (int m = t; m < NPTS; m += 256) {
      float v = dist[m];
      if (v < bv || (v == bv && m < bi)) { bv = v; bi = m; }
    }
    rv[t] = bv; ri[t] = bi;
    __syncthreads();
    for (int s = 128; s > 0; s >>= 1) {
      if (t < s) {
        float v2 = rv[t+s]; int i2 = ri[t+s];
        if (v2 < rv[t] || (v2 == rv[t] && i2 < ri[t])) { rv[t] = v2; ri[t] = i2; }
      }
      __syncthreads();
    }
    if (t == 0) {
      idxout[bn*KNNK + k] = ri[0];
      dist[ri[0]] = 3.0e38f;
    }
    __syncthreads();
  }
}

// --- stage 128 edge-feature rows (8 points x 16 nbrs) into swizzled bf16 LDS ---
__device__ inline void stage_feat(short* featS, const float* __restrict__ h,
                                  const int* __restrict__ idx, int b, int n0, int t) {
  int r = t >> 1, cb = (t & 1) * 32;
  int p = r >> 4, kk = r & 15;
  int nbi = idx[(size_t)(b*NPTS + n0 + p)*KNNK + kk];
  const float* hq = h + (size_t)(b*NPTS + n0 + p)*CH;
  const float* hn = h + (size_t)(b*NPTS + nbi)*CH;
#pragma unroll
  for (int j = 0; j < 32; j += 8) {
    float4 q0 = *(const float4*)(hq + cb + j);
    float4 q1 = *(const float4*)(hq + cb + j + 4);
    float4 a0 = *(const float4*)(hn + cb + j);
    float4 a1 = *(const float4*)(hn + cb + j + 4);
    short8v d, qv;
    d[0]=f2bf(a0.x-q0.x); d[1]=f2bf(a0.y-q0.y); d[2]=f2bf(a0.z-q0.z); d[3]=f2bf(a0.w-q0.w);
    d[4]=f2bf(a1.x-q1.x); d[5]=f2bf(a1.y-q1.y); d[6]=f2bf(a1.z-q1.z); d[7]=f2bf(a1.w-q1.w);
    qv[0]=f2bf(q0.x); qv[1]=f2bf(q0.y); qv[2]=f2bf(q0.z); qv[3]=f2bf(q0.w);
    qv[4]=f2bf(q1.x); qv[5]=f2bf(q1.y); qv[6]=f2bf(q1.z); qv[7]=f2bf(q1.w);
    *(short8v*)&featS[LIDX(r, cb + j, CF)] = d;
    *(short8v*)&featS[LIDX(r, 64 + cb + j, CF)] = qv;
  }
}

// GEMM1 only, accumulate GroupNorm partial sums per (block, group)
__global__ __launch_bounds__(256, 2)
void k_stats(const float* __restrict__ h, const int* __restrict__ idx,
             const short* __restrict__ W1p, float* __restrict__ partials) {
  __shared__ short featS[MROWS*CF];
  int blk = blockIdx.x;
  int b = blk >> 8;
  int n0 = (blk & 255) * P;
  int t = threadIdx.x;
  stage_feat(featS, h, idx, b, n0, t);
  __syncthreads();
  int lane = t & 63, wv = t >> 6;
  int r16 = lane & 15, g8 = (lane >> 4) * 8;
  short8v af[8][4];
#pragma unroll
  for (int m = 0; m < 8; ++m)
#pragma unroll
    for (int ks = 0; ks < 4; ++ks)
      af[m][ks] = *(const short8v*)&featS[LIDX(m*16 + r16, ks*32 + g8, CF)];
  float s = 0.f, ss = 0.f;
#pragma unroll
  for (int n = 0; n < 2; ++n) {
    int nt = 2*wv + n;
    short8v bfr[4];
#pragma unroll
    for (int ks = 0; ks < 4; ++ks)
      bfr[ks] = *(const short8v*)&W1p[(size_t)((nt*4 + ks)*64 + lane)*8];
#pragma unroll
    for (int m = 0; m < 8; ++m) {
      f32x4 acc = {0.f, 0.f, 0.f, 0.f};
#pragma unroll
      for (int ks = 0; ks < 4; ++ks)
        acc = __builtin_amdgcn_mfma_f32_16x16x32_bf16(af[m][ks], bfr[ks], acc, 0, 0, 0);
#pragma unroll
      for (int i = 0; i < 4; ++i) { s += acc[i]; ss += acc[i]*acc[i]; }
    }
  }
#pragma unroll
  for (int off = 32; off > 0; off >>= 1) {
    s += __shfl_xor(s, off);
    ss += __shfl_xor(ss, off);
  }
  if (lane == 0) {
    partials[(size_t)(blk*NGRP + wv)*2 + 0] = s;
    partials[(size_t)(blk*NGRP + wv)*2 + 1] = ss;
  }
}

__global__ void k_reduce(const float* __restrict__ partials, float* __restrict__ stats) {
  int b = blockIdx.x >> 2, g = blockIdx.x & 3;
  int t = threadIdx.x;
  float s  = partials[(size_t)((b*256 + t)*NGRP + g)*2 + 0];
  float ss = partials[(size_t)((b*256 + t)*NGRP + g)*2 + 1];
  __shared__ float rs[256], rss[256];
  rs[t] = s; rss[t] = ss;
  __syncthreads();
  for (int st = 128; st > 0; st >>= 1) {
    if (t < st) { rs[t] += rs[t+st]; rss[t] += rss[t+st]; }
    __syncthreads();
  }
  if (t == 0) {
    const float cnt = (float)((size_t)NPTS * KNNK * 32);
    float mu = rs[0] / cnt;
    float var = rss[0] / cnt - mu*mu;
    stats[(b*NGRP+g)*2+0] = mu;
    stats[(b*NGRP+g)*2+1] = rsqrtf(var + EPSF);
  }
}

__global__ __launch_bounds__(256, 1)
void k_main(const float* __restrict__ h, const int* __restrict__ idx,
            const short* __restrict__ W1p, const float* __restrict__ gng,
            const float* __restrict__ gnb, const float* __restrict__ stats,
            const short* __restrict__ Wap, const float* __restrict__ ba,
            const short* __restrict__ Wbp, const float* __restrict__ bb,
            float* __restrict__ lbase, unsigned* __restrict__ gmaxU) {
  __shared__ short featS[MROWS*CF];   // 32 KB
  __shared__ short ynS[MROWS*CF];     // 32 KB
  __shared__ short g1S[MROWS*CA];     // 64 KB
  int blk = blockIdx.x;
  int b = blk >> 8;
  int n0 = (blk & 255) * P;
  int t = threadIdx.x;
  stage_feat(featS, h, idx, b, n0, t);
  __syncthreads();
  int lane = t & 63, wv = t >> 6;
  int r16 = lane & 15, g8 = (lane >> 4) * 8;
  int rowg = (lane >> 4) * 4;
  // ---- GEMM1: y = feat @ W1^T, GN affine + leaky, -> ynS (bf16) + lbase ----
  {
    short8v af[8][4];
#pragma unroll
    for (int m = 0; m < 8; ++m)
#pragma unroll
      for (int ks = 0; ks < 4; ++ks)
        af[m][ks] = *(const short8v*)&featS[LIDX(m*16 + r16, ks*32 + g8, CF)];
    float mu  = stats[(b*NGRP + wv)*2 + 0];
    float rsg = stats[(b*NGRP + wv)*2 + 1];
#pragma unroll
    for (int n = 0; n < 2; ++n) {
      int nt = 2*wv + n;
      int o = nt*16 + r16;
      short8v bfr[4];
#pragma unroll
      for (int ks = 0; ks < 4; ++ks)
        bfr[ks] = *(const short8v*)&W1p[(size_t)((nt*4 + ks)*64 + lane)*8];
      float ga = gng[o], bev = gnb[o];
#pragma unroll
      for (int m = 0; m < 8; ++m) {
        f32x4 acc = {0.f, 0.f, 0.f, 0.f};
#pragma unroll
        for (int ks = 0; ks < 4; ++ks)
          acc = __builtin_amdgcn_mfma_f32_16x16x32_bf16(af[m][ks], bfr[ks], acc, 0, 0, 0);
        float vmax = -3.0e38f;
#pragma unroll
        for (int i = 0; i < 4; ++i) {
          float v = (acc[i] - mu) * rsg * ga + bev;
          v = (v >= 0.f) ? v : 0.2f*v;
          vmax = fmaxf(vmax, v);
          ynS[LIDX(m*16 + rowg + i, o, CF)] = f2bf(v);
        }
        vmax = fmaxf(vmax, __shfl_xor(vmax, 16));
        vmax = fmaxf(vmax, __shfl_xor(vmax, 32));
        if (lane < 16) lbase[(size_t)(b*NPTS + n0 + m)*CF + o] = vmax;
      }
    }
  }
  __syncthreads();
  // ---- GEMM2: g1 = relu(yn @ Wa^T + ba) -> g1S (bf16) ----
  {
    short8v yf[8][4];
#pragma unroll
    for (int m = 0; m < 8; ++m)
#pragma unroll
      for (int ks = 0; ks < 4; ++ks)
        yf[m][ks] = *(const short8v*)&ynS[LIDX(m*16 + r16, ks*32 + g8, CF)];
#pragma unroll
    for (int nn = 0; nn < 4; ++nn) {
      int nt = wv*4 + nn;
      int o = nt*16 + r16;
      short8v bfr[4];
#pragma unroll
      for (int ks = 0; ks < 4; ++ks)
        bfr[ks] = *(const short8v*)&Wap[(size_t)((nt*4 + ks)*64 + lane)*8];
      float bav = ba[o];
#pragma unroll
      for (int m = 0; m < 8; ++m) {
        f32x4 acc = {0.f, 0.f, 0.f, 0.f};
#pragma unroll
        for (int ks = 0; ks < 4; ++ks)
          acc = __builtin_amdgcn_mfma_f32_16x16x32_bf16(yf[m][ks], bfr[ks], acc, 0, 0, 0);
#pragma unroll
        for (int i = 0; i < 4; ++i) {
          float v = fmaxf(acc[i] + bav, 0.f);
          g1S[LIDX(m*16 + rowg + i, o, CA)] = f2bf(v);
        }
      }
    }
  }
  __syncthreads();
  // ---- GEMM3: g2 = g1 @ Wb^T + bb, max over k & points, atomicMax over n ----
  {
    short8v gf[8][8];
#pragma unroll
    for (int m = 0; m < 8; ++m)
#pragma unroll
      for (int ks = 0; ks < 8; ++ks)
        gf[m][ks] = *(const short8v*)&g1S[LIDX(m*16 + r16, ks*32 + g8, CA)];
#pragma unroll
    for (int nn = 0; nn < 8; ++nn) {
      int nt = wv*8 + nn;
      short8v bfr[8];
#pragma unroll
      for (int ks = 0; ks < 8; ++ks)
        bfr[ks] = *(const short8v*)&Wbp[(size_t)((nt*8 + ks)*64 + lane)*8];
      f32x4 acc[8];
#pragma unroll
      for (int m = 0; m < 8; ++m) acc[m] = (f32x4){0.f, 0.f, 0.f, 0.f};
#pragma unroll
      for (int ks = 0; ks < 8; ++ks)
#pragma unroll
        for (int m = 0; m < 8; ++m)
          acc[m] = __builtin_amdgcn_mfma_f32_16x16x32_bf16(gf[m][ks], bfr[ks], acc[m], 0, 0, 0);
      float b0 = bb[nt*16 + r16];
      float am = 0.f;  // relu fold
#pragma unroll
      for (int m = 0; m < 8; ++m)
#pragma unroll
        for (int i = 0; i < 4; ++i) am = fmaxf(am, acc[m][i] + b0);
      am = fmaxf(am, __shfl_xor(am, 16));
      am = fmaxf(am, __shfl_xor(am, 32));
      if (lane < 16) atomicMax(&gmaxU[b*CG + nt*16 + lane], __float_as_uint(am));
    }
  }
}

__global__ __launch_bounds__(256)
void k_tail(const float* __restrict__ lbase, const unsigned* __restrict__ gmaxU,
            const float* __restrict__ WcT, const float* __restrict__ bc,
            const float* __restrict__ WdT, const float* __restrict__ bd,
            const float* __restrict__ WeT, const float* __restrict__ be,
            const float* __restrict__ WfT, const float* __restrict__ bf,
            float* __restrict__ out, unsigned* __restrict__ glmaxU) {
  __shared__ float cat[TN][CCAT];
  __shared__ float lf1s[TN][CC];
  __shared__ float lf2s[TN][CD];
  __shared__ float gl1s[TN][CE];
  int blk = blockIdx.x;
  int b = blk >> 8;
  int n0 = (blk & 255) * TN;
  int t = threadIdx.x;
  for (int i = t; i < TN*CF; i += 256) {
    int nn = i >> 7, c = i & 127;
    cat[nn][c] = lbase[((size_t)(b*NPTS + n0 + nn))*CF + c];
  }
  for (int i = t; i < CB; i += 256) {
    float g = __uint_as_float(gmaxU[b*CB + i]);
#pragma unroll
    for (int nn = 0; nn < TN; ++nn) cat[nn][CF + i] = g;
  }
  __syncthreads();
  {
    float acc[TN];
#pragma unroll
    for (int nn = 0; nn < TN; ++nn) acc[nn] = 0.f;
    for (int c = 0; c < CCAT; ++c) {
      float wv = WcT[c*CC + t];
#pragma unroll
      for (int nn = 0; nn < TN; ++nn) acc[nn] += cat[nn][c]*wv;
    }
    float bv = bc[t];
#pragma unroll
    for (int nn = 0; nn < TN; ++nn) lf1s[nn][t] = fmaxf(acc[nn]+bv, 0.f);
  }
  __syncthreads();
  if (t < CD) {
    float acc[TN];
#pragma unroll
    for (int nn = 0; nn < TN; ++nn) acc[nn] = 0.f;
    for (int c = 0; c < CC; ++c) {
      float wv = WdT[c*CD + t];
#pragma unroll
      for (int nn = 0; nn < TN; ++nn) acc[nn] += lf1s[nn][c]*wv;
    }
    float bv = bd[t];
#pragma unroll
    for (int nn = 0; nn < TN; ++nn) {
      float v = fmaxf(acc[nn]+bv, 0.f);
      lf2s[nn][t] = v;
      out[GF_OFF + ((size_t)(b*CD + t))*NPTS + n0 + nn] = v;
    }
  }
  __syncthreads();
  {
    float acc[TN];
#pragma unroll
    for (int nn = 0; nn < TN; ++nn) acc[nn] = 0.f;
    for (int c = 0; c < CD; ++c) {
      float wv = WeT[c*CE + t];
#pragma unroll
      for (int nn = 0; nn < TN; ++nn) acc[nn] += lf2s[nn][c]*wv;
    }
    float bv = be[t];
#pragma unroll
    for (int nn = 0; nn < TN; ++nn) gl1s[nn][t] = fmaxf(acc[nn]+bv, 0.f);
  }
  __syncthreads();
  {
    float a0[TN], a1[TN];
#pragma unroll
    for (int nn = 0; nn < TN; ++nn) { a0[nn] = 0.f; a1[nn] = 0.f; }
    for (int c = 0; c < CE; ++c) {
      float w0 = WfT[c*CG + t];
      float w1 = WfT[c*CG + t + 256];
#pragma unroll
      for (int nn = 0; nn < TN; ++nn) {
        float v = gl1s[nn][c];
        a0[nn] += v*w0; a1[nn] += v*w1;
      }
    }
    float b0 = bf[t], b1 = bf[t+256];
    float m0 = 0.f, m1 = 0.f;
#pragma unroll
    for (int nn = 0; nn < TN; ++nn) { m0 = fmaxf(m0, a0[nn]+b0); m1 = fmaxf(m1, a1[nn]+b1); }
    atomicMax(&glmaxU[b*CG + t], __float_as_uint(m0));
    atomicMax(&glmaxU[b*CG + t + 256], __float_as_uint(m1));
  }
}

__global__ void k_final(const unsigned* __restrict__ glmaxU, float* __restrict__ out) {
  int i = blockIdx.x*256 + threadIdx.x;
  if (i < BATCH*CG) out[i] = __uint_as_float(glmaxU[i]);
}

extern "C" void kernel_launch(void* const* d_in, const int* in_sizes, int n_in,
                              void* d_out, int out_size, void* d_ws, size_t ws_size,
                              hipStream_t stream) {
  const float* x   = (const float*)d_in[0];
  const float* f   = (const float*)d_in[1];
  const float* Wit = (const float*)d_in[2];
  const float* bit = (const float*)d_in[3];
  const float* W1  = (const float*)d_in[4];
  const float* gng = (const float*)d_in[5];
  const float* gnb = (const float*)d_in[6];
  const float* Wa  = (const float*)d_in[7];
  const float* ba  = (const float*)d_in[8];
  const float* Wb  = (const float*)d_in[9];
  const float* bb  = (const float*)d_in[10];
  const float* Wc  = (const float*)d_in[11];
  const float* bc  = (const float*)d_in[12];
  const float* Wd  = (const float*)d_in[13];
  const float* bd  = (const float*)d_in[14];
  const float* We  = (const float*)d_in[15];
  const float* be  = (const float*)d_in[16];
  const float* Wf  = (const float*)d_in[17];
  const float* bf  = (const float*)d_in[18];
  float* out = (float*)d_out;

  char* w = (char*)d_ws;
  size_t off = 0;
  auto alloc = [&](size_t bytes) {
    void* p = w + off; off += (bytes + 255) & ~(size_t)255; return p;
  };
  float* h        = (float*)alloc((size_t)BATCH*NPTS*CH*4);
  float* sq       = (float*)alloc((size_t)BATCH*NPTS*4);
  int*   idx      = (int*)  alloc((size_t)BATCH*NPTS*KNNK*4);
  short* W1p      = (short*)alloc((size_t)CF*CF*2);
  short* Wap      = (short*)alloc((size_t)CA*CF*2);
  short* Wbp      = (short*)alloc((size_t)CB*CA*2);
  float* WcT      = (float*)alloc((size_t)CCAT*CC*4);
  float* WdT      = (float*)alloc((size_t)CC*CD*4);
  float* WeT      = (float*)alloc((size_t)CD*CE*4);
  float* WfT      = (float*)alloc((size_t)CE*CG*4);
  float* partials = (float*)alloc((size_t)(BATCH*NPTS/P)*NGRP*2*4);
  float* stats    = (float*)alloc((size_t)BATCH*NGRP*2*4);
  float* lbase    = (float*)alloc((size_t)BATCH*NPTS*CF*4);
  unsigned* gmaxU  = (unsigned*)alloc((size_t)BATCH*CG*4);
  unsigned* glmaxU = (unsigned*)alloc((size_t)BATCH*CG*4);

  hipMemsetAsync(gmaxU, 0, (size_t)BATCH*CG*4, stream);
  hipMemsetAsync(glmaxU, 0, (size_t)BATCH*CG*4, stream);

  k_pack<<<(CF/16*CF/32*64 + 255)/256, 256, 0, stream>>>(W1, W1p, CF, CF);
  k_pack<<<(CA/16*CF/32*64 + 255)/256, 256, 0, stream>>>(Wa, Wap, CA, CF);
  k_pack<<<(CB/16*CA/32*64 + 255)/256, 256, 0, stream>>>(Wb, Wbp, CB, CA);
  k_transpose<<<(CC*CCAT+255)/256, 256, 0, stream>>>(Wc, WcT, CC, CCAT);
  k_transpose<<<(CD*CC+255)/256, 256, 0, stream>>>(Wd, WdT, CD, CC);
  k_transpose<<<(CE*CD+255)/256, 256, 0, stream>>>(We, WeT, CE, CD);
  k_transpose<<<(CG*CE+255)/256, 256, 0, stream>>>(Wf, WfT, CG, CE);

  k_sq_h<<<(BATCH*NPTS*CH+255)/256, 256, 0, stream>>>(x, f, Wit, bit, sq, h);
  k_knn<<<BATCH*NPTS, 256, 0, stream>>>(x, sq, idx);
  k_stats<<<BATCH*NPTS/P, 256, 0, stream>>>(h, idx, W1p, partials);
  k_reduce<<<BATCH*NGRP, 256, 0, stream>>>(partials, stats);
  k_main<<<BATCH*NPTS/P, 256, 0, stream>>>(h, idx, W1p, gng, gnb, stats,
                                           Wap, ba, Wbp, bb, lbase, gmaxU);
  k_tail<<<BATCH*NPTS/TN, 256, 0, stream>>>(lbase, gmaxU, WcT, bc, WdT, bd,
                                            WeT, be, WfT, bf, out, glmaxU);
  k_final<<<(BATCH*CG+255)/256, 256, 0, stream>>>(glmaxU, out);
}

// Round 3
// 603.713 us; speedup vs baseline: 3.2537x; 1.3336x over previous
//
#include <hip/hip_runtime.h>

#define BATCH 8
#define NPTS 2048
#define KNNK 16
#define CH 64
#define CF 128
#define CA 256
#define CB 512
#define CCAT 640
#define CC 256
#define CD 128
#define CE 256
#define CG 512
#define NGRP 4
#define EPSF 1e-5f
#define GF_OFF (BATCH*CG)
#define TN 16
#define P 8              // points per MFMA block
#define MROWS (P*KNNK)   // 128 rows

typedef __attribute__((ext_vector_type(8))) short short8v;
typedef __attribute__((ext_vector_type(4))) float f32x4;

__device__ inline short f2bf(float f) {
  union { float f; unsigned u; } v; v.f = f;
  unsigned r = v.u + 0x7fff + ((v.u >> 16) & 1);
  return (short)(r >> 16);
}

// XOR-swizzled LDS element index (bf16 elements; flips 16B slot within 128B)
#define LIDX(r, c, ROW) ((r)*(ROW) + ((c) ^ (((r)&7)<<3)))

// dst[c*R + r] = src[r*C + c]
__global__ void k_transpose(const float* __restrict__ src, float* __restrict__ dst,
                            int R, int C) {
  int i = blockIdx.x * 256 + threadIdx.x;
  if (i < R * C) {
    int r = i / C, c = i - r * C;
    dst[c * R + r] = src[i];
  }
}

// pack W[O][C] (f32) into MFMA B-fragment-linear bf16
__global__ void k_pack(const float* __restrict__ W, short* __restrict__ Wp,
                       int O, int C) {
  int tid = blockIdx.x * 256 + threadIdx.x;
  int KS = C >> 5;
  int total = (O >> 4) * KS * 64;
  if (tid >= total) return;
  int l = tid & 63;
  int fs = tid >> 6;
  int nt = fs / KS, ks = fs - nt * KS;
  int o = nt * 16 + (l & 15);
  int c = ks * 32 + (l >> 4) * 8;
  const float* src = W + (size_t)o * C + c;
  short8v v;
#pragma unroll
  for (int j = 0; j < 8; ++j) v[j] = f2bf(src[j]);
  *(short8v*)&Wp[(size_t)tid * 8] = v;
}

__global__ void k_sq_h(const float* __restrict__ x, const float* __restrict__ f,
                       const float* __restrict__ Wit, const float* __restrict__ bit,
                       float* __restrict__ h) {
  int t = blockIdx.x * 256 + threadIdx.x;
  if (t >= BATCH * NPTS * CH) return;
  int o = t & (CH - 1);
  int bn = t >> 6;
  int n = bn & (NPTS - 1);
  int b = bn >> 11;
  float f0 = f[(b*3 + 0)*NPTS + n];
  float f1 = f[(b*3 + 1)*NPTS + n];
  float f2 = f[(b*3 + 2)*NPTS + n];
  h[t] = f0*Wit[o*3+0] + f1*Wit[o*3+1] + f2*Wit[o*3+2] + bit[o];
}

// one wave per query; lane owns candidate chunk [32*lane, 32*lane+32)
__global__ __launch_bounds__(256)
void k_knn(const float* __restrict__ x, int* __restrict__ idxout) {
  __shared__ float xs0[2112], xs1[2112], xs2[2112], sqs[2112];
  int blk = blockIdx.x;
  int b = blk >> 9;               // 512 blocks per batch
  int n0 = (blk & 511) * 4;
  int t = threadIdx.x;
  // stage x (pad-33) + sq into LDS (exact numpy rounding for sq)
  for (int i = t; i < NPTS; i += 256) {
    float x0 = x[(b*3 + 0)*NPTS + i];
    float x1 = x[(b*3 + 1)*NPTS + i];
    float x2 = x[(b*3 + 2)*NPTS + i];
    int a = (i >> 5)*33 + (i & 31);
    xs0[a] = x0; xs1[a] = x1; xs2[a] = x2;
    sqs[a] = __fadd_rn(__fadd_rn(__fmul_rn(x0,x0), __fmul_rn(x1,x1)), __fmul_rn(x2,x2));
  }
  __syncthreads();
  int lane = t & 63, wv = t >> 6;
  int q = n0 + wv;
  int qa = (q >> 5)*33 + (q & 31);
  float qx = xs0[qa], qy = xs1[qa], qz = xs2[qa];
  float sqq = sqs[qa];
  // per-lane distances (exact rounding identical to reference emulation)
  float d[32];
  int base = lane * 32;
#pragma unroll
  for (int jj = 0; jj < 32; ++jj) {
    int a = lane*33 + jj;
    float mx = xs0[a], my = xs1[a], mz = xs2[a];
    float dot = __fadd_rn(__fadd_rn(__fmul_rn(qx,mx), __fmul_rn(qy,my)), __fmul_rn(qz,mz));
    d[jj] = __fsub_rn(__fadd_rn(sqq, sqs[a]), __fadd_rn(dot, dot));
  }
  const float FINF = __builtin_inff();
  // two sub-chunk minima (strict < keeps lowest index)
  float sv0 = d[0]; int si0 = base;
#pragma unroll
  for (int jj = 1; jj < 16; ++jj)
    if (d[jj] < sv0) { sv0 = d[jj]; si0 = base + jj; }
  float sv1 = d[16]; int si1 = base + 16;
#pragma unroll
  for (int jj = 17; jj < 32; ++jj)
    if (d[jj] < sv1) { sv1 = d[jj]; si1 = base + jj; }
  int gsel = 0;
#pragma unroll
  for (int r = 0; r < KNNK; ++r) {
    float v = sv0; int i = si0;
    if (sv1 < v || (sv1 == v && si1 < i)) { v = sv1; i = si1; }
#pragma unroll
    for (int off = 32; off > 0; off >>= 1) {
      float v2 = __shfl_xor(v, off);
      int   i2 = __shfl_xor(i, off);
      if (v2 < v || (v2 == v && i2 < i)) { v = v2; i = i2; }
    }
    if (lane == r) gsel = i;
    int rem = ((i >> 5) == lane) ? (i & 31) : 64;
    if (rem < 16) {
      float nv = FINF; int ni = 0x7fffffff;
#pragma unroll
      for (int jj = 0; jj < 16; ++jj) {
        float dv = (jj == rem) ? FINF : d[jj];
        d[jj] = dv;
        if (dv < nv) { nv = dv; ni = base + jj; }
      }
      sv0 = nv; si0 = ni;
    } else if (rem < 32) {
      float nv = FINF; int ni = 0x7fffffff;
#pragma unroll
      for (int jj = 16; jj < 32; ++jj) {
        float dv = (jj == rem) ? FINF : d[jj];
        d[jj] = dv;
        if (dv < nv) { nv = dv; ni = base + jj; }
      }
      sv1 = nv; si1 = ni;
    }
  }
  if (lane < KNNK) idxout[(size_t)(b*NPTS + q)*KNNK + lane] = gsel;
}

// --- stage 128 edge-feature rows (8 points x 16 nbrs) into swizzled bf16 LDS ---
__device__ inline void stage_feat(short* featS, const float* __restrict__ h,
                                  const int* __restrict__ idx, int b, int n0, int t) {
  int r = t >> 1, cb = (t & 1) * 32;
  int p = r >> 4, kk = r & 15;
  int nbi = idx[(size_t)(b*NPTS + n0 + p)*KNNK + kk];
  const float* hq = h + (size_t)(b*NPTS + n0 + p)*CH;
  const float* hn = h + (size_t)(b*NPTS + nbi)*CH;
#pragma unroll
  for (int j = 0; j < 32; j += 8) {
    float4 q0 = *(const float4*)(hq + cb + j);
    float4 q1 = *(const float4*)(hq + cb + j + 4);
    float4 a0 = *(const float4*)(hn + cb + j);
    float4 a1 = *(const float4*)(hn + cb + j + 4);
    short8v dv, qv;
    dv[0]=f2bf(a0.x-q0.x); dv[1]=f2bf(a0.y-q0.y); dv[2]=f2bf(a0.z-q0.z); dv[3]=f2bf(a0.w-q0.w);
    dv[4]=f2bf(a1.x-q1.x); dv[5]=f2bf(a1.y-q1.y); dv[6]=f2bf(a1.z-q1.z); dv[7]=f2bf(a1.w-q1.w);
    qv[0]=f2bf(q0.x); qv[1]=f2bf(q0.y); qv[2]=f2bf(q0.z); qv[3]=f2bf(q0.w);
    qv[4]=f2bf(q1.x); qv[5]=f2bf(q1.y); qv[6]=f2bf(q1.z); qv[7]=f2bf(q1.w);
    *(short8v*)&featS[LIDX(r, cb + j, CF)] = dv;
    *(short8v*)&featS[LIDX(r, 64 + cb + j, CF)] = qv;
  }
}

// GEMM1 only, accumulate GroupNorm partial sums per (block, group)
__global__ __launch_bounds__(256, 2)
void k_stats(const float* __restrict__ h, const int* __restrict__ idx,
             const short* __restrict__ W1p, float* __restrict__ partials) {
  __shared__ short featS[MROWS*CF];
  int blk = blockIdx.x;
  int b = blk >> 8;
  int n0 = (blk & 255) * P;
  int t = threadIdx.x;
  stage_feat(featS, h, idx, b, n0, t);
  __syncthreads();
  int lane = t & 63, wv = t >> 6;
  int r16 = lane & 15, g8 = (lane >> 4) * 8;
  short8v af[8][4];
#pragma unroll
  for (int m = 0; m < 8; ++m)
#pragma unroll
    for (int ks = 0; ks < 4; ++ks)
      af[m][ks] = *(const short8v*)&featS[LIDX(m*16 + r16, ks*32 + g8, CF)];
  float s = 0.f, ss = 0.f;
#pragma unroll
  for (int n = 0; n < 2; ++n) {
    int nt = 2*wv + n;
    short8v bfr[4];
#pragma unroll
    for (int ks = 0; ks < 4; ++ks)
      bfr[ks] = *(const short8v*)&W1p[(size_t)((nt*4 + ks)*64 + lane)*8];
#pragma unroll
    for (int m = 0; m < 8; ++m) {
      f32x4 acc = {0.f, 0.f, 0.f, 0.f};
#pragma unroll
      for (int ks = 0; ks < 4; ++ks)
        acc = __builtin_amdgcn_mfma_f32_16x16x32_bf16(af[m][ks], bfr[ks], acc, 0, 0, 0);
#pragma unroll
      for (int i = 0; i < 4; ++i) { s += acc[i]; ss += acc[i]*acc[i]; }
    }
  }
#pragma unroll
  for (int off = 32; off > 0; off >>= 1) {
    s += __shfl_xor(s, off);
    ss += __shfl_xor(ss, off);
  }
  if (lane == 0) {
    partials[(size_t)(blk*NGRP + wv)*2 + 0] = s;
    partials[(size_t)(blk*NGRP + wv)*2 + 1] = ss;
  }
}

__global__ void k_reduce(const float* __restrict__ partials, float* __restrict__ stats) {
  int b = blockIdx.x >> 2, g = blockIdx.x & 3;
  int t = threadIdx.x;
  float s  = partials[(size_t)((b*256 + t)*NGRP + g)*2 + 0];
  float ss = partials[(size_t)((b*256 + t)*NGRP + g)*2 + 1];
  __shared__ float rs[256], rss[256];
  rs[t] = s; rss[t] = ss;
  __syncthreads();
  for (int st = 128; st > 0; st >>= 1) {
    if (t < st) { rs[t] += rs[t+st]; rss[t] += rss[t+st]; }
    __syncthreads();
  }
  if (t == 0) {
    const float cnt = (float)((size_t)NPTS * KNNK * 32);
    float mu = rs[0] / cnt;
    float var = rss[0] / cnt - mu*mu;
    stats[(b*NGRP+g)*2+0] = mu;
    stats[(b*NGRP+g)*2+1] = rsqrtf(var + EPSF);
  }
}

__global__ __launch_bounds__(256, 1)
void k_main(const float* __restrict__ h, const int* __restrict__ idx,
            const short* __restrict__ W1p, const float* __restrict__ gng,
            const float* __restrict__ gnb, const float* __restrict__ stats,
            const short* __restrict__ Wap, const float* __restrict__ ba,
            const short* __restrict__ Wbp, const float* __restrict__ bb,
            float* __restrict__ lbase, unsigned* __restrict__ gmaxU) {
  __shared__ short featS[MROWS*CF];   // 32 KB
  __shared__ short ynS[MROWS*CF];     // 32 KB
  __shared__ short g1S[MROWS*CA];     // 64 KB
  int blk = blockIdx.x;
  int b = blk >> 8;
  int n0 = (blk & 255) * P;
  int t = threadIdx.x;
  stage_feat(featS, h, idx, b, n0, t);
  __syncthreads();
  int lane = t & 63, wv = t >> 6;
  int r16 = lane & 15, g8 = (lane >> 4) * 8;
  int rowg = (lane >> 4) * 4;
  // ---- GEMM1: y = feat @ W1^T, GN affine + leaky, -> ynS (bf16) + lbase ----
  {
    short8v af[8][4];
#pragma unroll
    for (int m = 0; m < 8; ++m)
#pragma unroll
      for (int ks = 0; ks < 4; ++ks)
        af[m][ks] = *(const short8v*)&featS[LIDX(m*16 + r16, ks*32 + g8, CF)];
    float mu  = stats[(b*NGRP + wv)*2 + 0];
    float rsg = stats[(b*NGRP + wv)*2 + 1];
#pragma unroll
    for (int n = 0; n < 2; ++n) {
      int nt = 2*wv + n;
      int o = nt*16 + r16;
      short8v bfr[4];
#pragma unroll
      for (int ks = 0; ks < 4; ++ks)
        bfr[ks] = *(const short8v*)&W1p[(size_t)((nt*4 + ks)*64 + lane)*8];
      float ga = gng[o], bev = gnb[o];
#pragma unroll
      for (int m = 0; m < 8; ++m) {
        f32x4 acc = {0.f, 0.f, 0.f, 0.f};
#pragma unroll
        for (int ks = 0; ks < 4; ++ks)
          acc = __builtin_amdgcn_mfma_f32_16x16x32_bf16(af[m][ks], bfr[ks], acc, 0, 0, 0);
        float vmax = -3.0e38f;
#pragma unroll
        for (int i = 0; i < 4; ++i) {
          float v = (acc[i] - mu) * rsg * ga + bev;
          v = (v >= 0.f) ? v : 0.2f*v;
          vmax = fmaxf(vmax, v);
          ynS[LIDX(m*16 + rowg + i, o, CF)] = f2bf(v);
        }
        vmax = fmaxf(vmax, __shfl_xor(vmax, 16));
        vmax = fmaxf(vmax, __shfl_xor(vmax, 32));
        if (lane < 16) lbase[(size_t)(b*NPTS + n0 + m)*CF + o] = vmax;
      }
    }
  }
  __syncthreads();
  // ---- GEMM2: g1 = relu(yn @ Wa^T + ba) -> g1S (bf16) ----
  {
    short8v yf[8][4];
#pragma unroll
    for (int m = 0; m < 8; ++m)
#pragma unroll
      for (int ks = 0; ks < 4; ++ks)
        yf[m][ks] = *(const short8v*)&ynS[LIDX(m*16 + r16, ks*32 + g8, CF)];
#pragma unroll
    for (int nn = 0; nn < 4; ++nn) {
      int nt = wv*4 + nn;
      int o = nt*16 + r16;
      short8v bfr[4];
#pragma unroll
      for (int ks = 0; ks < 4; ++ks)
        bfr[ks] = *(const short8v*)&Wap[(size_t)((nt*4 + ks)*64 + lane)*8];
      float bav = ba[o];
#pragma unroll
      for (int m = 0; m < 8; ++m) {
        f32x4 acc = {0.f, 0.f, 0.f, 0.f};
#pragma unroll
        for (int ks = 0; ks < 4; ++ks)
          acc = __builtin_amdgcn_mfma_f32_16x16x32_bf16(yf[m][ks], bfr[ks], acc, 0, 0, 0);
#pragma unroll
        for (int i = 0; i < 4; ++i) {
          float v = fmaxf(acc[i] + bav, 0.f);
          g1S[LIDX(m*16 + rowg + i, o, CA)] = f2bf(v);
        }
      }
    }
  }
  __syncthreads();
  // ---- GEMM3: g2 = g1 @ Wb^T + bb, max over k & points, atomicMax over n ----
  {
    short8v gf[8][8];
#pragma unroll
    for (int m = 0; m < 8; ++m)
#pragma unroll
      for (int ks = 0; ks < 8; ++ks)
        gf[m][ks] = *(const short8v*)&g1S[LIDX(m*16 + r16, ks*32 + g8, CA)];
#pragma unroll
    for (int nn = 0; nn < 8; ++nn) {
      int nt = wv*8 + nn;
      short8v bfr[8];
#pragma unroll
      for (int ks = 0; ks < 8; ++ks)
        bfr[ks] = *(const short8v*)&Wbp[(size_t)((nt*8 + ks)*64 + lane)*8];
      f32x4 acc[8];
#pragma unroll
      for (int m = 0; m < 8; ++m) acc[m] = (f32x4){0.f, 0.f, 0.f, 0.f};
#pragma unroll
      for (int ks = 0; ks < 8; ++ks)
#pragma unroll
        for (int m = 0; m < 8; ++m)
          acc[m] = __builtin_amdgcn_mfma_f32_16x16x32_bf16(gf[m][ks], bfr[ks], acc[m], 0, 0, 0);
      float b0 = bb[nt*16 + r16];
      float am = 0.f;  // relu fold
#pragma unroll
      for (int m = 0; m < 8; ++m)
#pragma unroll
        for (int i = 0; i < 4; ++i) am = fmaxf(am, acc[m][i] + b0);
      am = fmaxf(am, __shfl_xor(am, 16));
      am = fmaxf(am, __shfl_xor(am, 32));
      if (lane < 16) atomicMax(&gmaxU[b*CG + nt*16 + lane], __float_as_uint(am));
    }
  }
}

__global__ __launch_bounds__(256)
void k_tail(const float* __restrict__ lbase, const unsigned* __restrict__ gmaxU,
            const float* __restrict__ WcT, const float* __restrict__ bc,
            const float* __restrict__ WdT, const float* __restrict__ bd,
            const float* __restrict__ WeT, const float* __restrict__ be,
            const float* __restrict__ WfT, const float* __restrict__ bf,
            float* __restrict__ out, unsigned* __restrict__ glmaxU) {
  __shared__ float cat[TN][CCAT];
  __shared__ float lf1s[TN][CC];
  __shared__ float lf2s[TN][CD];
  __shared__ float gl1s[TN][CE];
  int blk = blockIdx.x;
  int b = blk >> 7;            // 128 blocks per batch
  int n0 = (blk & 127) * TN;
  int t = threadIdx.x;
  for (int i = t; i < TN*CF; i += 256) {
    int nn = i >> 7, c = i & 127;
    cat[nn][c] = lbase[((size_t)(b*NPTS + n0 + nn))*CF + c];
  }
  for (int i = t; i < CB; i += 256) {
    float g = __uint_as_float(gmaxU[b*CB + i]);
#pragma unroll
    for (int nn = 0; nn < TN; ++nn) cat[nn][CF + i] = g;
  }
  __syncthreads();
  {
    float acc[TN];
#pragma unroll
    for (int nn = 0; nn < TN; ++nn) acc[nn] = 0.f;
    for (int c = 0; c < CCAT; ++c) {
      float wv = WcT[c*CC + t];
#pragma unroll
      for (int nn = 0; nn < TN; ++nn) acc[nn] += cat[nn][c]*wv;
    }
    float bv = bc[t];
#pragma unroll
    for (int nn = 0; nn < TN; ++nn) lf1s[nn][t] = fmaxf(acc[nn]+bv, 0.f);
  }
  __syncthreads();
  if (t < CD) {
    float acc[TN];
#pragma unroll
    for (int nn = 0; nn < TN; ++nn) acc[nn] = 0.f;
    for (int c = 0; c < CC; ++c) {
      float wv = WdT[c*CD + t];
#pragma unroll
      for (int nn = 0; nn < TN; ++nn) acc[nn] += lf1s[nn][c]*wv;
    }
    float bv = bd[t];
#pragma unroll
    for (int nn = 0; nn < TN; ++nn) {
      float v = fmaxf(acc[nn]+bv, 0.f);
      lf2s[nn][t] = v;
      out[GF_OFF + ((size_t)(b*CD + t))*NPTS + n0 + nn] = v;
    }
  }
  __syncthreads();
  {
    float acc[TN];
#pragma unroll
    for (int nn = 0; nn < TN; ++nn) acc[nn] = 0.f;
    for (int c = 0; c < CD; ++c) {
      float wv = WeT[c*CE + t];
#pragma unroll
      for (int nn = 0; nn < TN; ++nn) acc[nn] += lf2s[nn][c]*wv;
    }
    float bv = be[t];
#pragma unroll
    for (int nn = 0; nn < TN; ++nn) gl1s[nn][t] = fmaxf(acc[nn]+bv, 0.f);
  }
  __syncthreads();
  {
    float a0[TN], a1[TN];
#pragma unroll
    for (int nn = 0; nn < TN; ++nn) { a0[nn] = 0.f; a1[nn] = 0.f; }
    for (int c = 0; c < CE; ++c) {
      float w0 = WfT[c*CG + t];
      float w1 = WfT[c*CG + t + 256];
#pragma unroll
      for (int nn = 0; nn < TN; ++nn) {
        float v = gl1s[nn][c];
        a0[nn] += v*w0; a1[nn] += v*w1;
      }
    }
    float b0 = bf[t], b1 = bf[t+256];
    float m0 = 0.f, m1 = 0.f;
#pragma unroll
    for (int nn = 0; nn < TN; ++nn) { m0 = fmaxf(m0, a0[nn]+b0); m1 = fmaxf(m1, a1[nn]+b1); }
    atomicMax(&glmaxU[b*CG + t], __float_as_uint(m0));
    atomicMax(&glmaxU[b*CG + t + 256], __float_as_uint(m1));
  }
}

__global__ void k_final(const unsigned* __restrict__ glmaxU, float* __restrict__ out) {
  int i = blockIdx.x*256 + threadIdx.x;
  if (i < BATCH*CG) out[i] = __uint_as_float(glmaxU[i]);
}

extern "C" void kernel_launch(void* const* d_in, const int* in_sizes, int n_in,
                              void* d_out, int out_size, void* d_ws, size_t ws_size,
                              hipStream_t stream) {
  const float* x   = (const float*)d_in[0];
  const float* f   = (const float*)d_in[1];
  const float* Wit = (const float*)d_in[2];
  const float* bit = (const float*)d_in[3];
  const float* W1  = (const float*)d_in[4];
  const float* gng = (const float*)d_in[5];
  const float* gnb = (const float*)d_in[6];
  const float* Wa  = (const float*)d_in[7];
  const float* ba  = (const float*)d_in[8];
  const float* Wb  = (const float*)d_in[9];
  const float* bb  = (const float*)d_in[10];
  const float* Wc  = (const float*)d_in[11];
  const float* bc  = (const float*)d_in[12];
  const float* Wd  = (const float*)d_in[13];
  const float* bd  = (const float*)d_in[14];
  const float* We  = (const float*)d_in[15];
  const float* be  = (const float*)d_in[16];
  const float* Wf  = (const float*)d_in[17];
  const float* bf  = (const float*)d_in[18];
  float* out = (float*)d_out;

  char* w = (char*)d_ws;
  size_t off = 0;
  auto alloc = [&](size_t bytes) {
    void* p = w + off; off += (bytes + 255) & ~(size_t)255; return p;
  };
  float* h        = (float*)alloc((size_t)BATCH*NPTS*CH*4);
  int*   idx      = (int*)  alloc((size_t)BATCH*NPTS*KNNK*4);
  short* W1p      = (short*)alloc((size_t)CF*CF*2);
  short* Wap      = (short*)alloc((size_t)CA*CF*2);
  short* Wbp      = (short*)alloc((size_t)CB*CA*2);
  float* WcT      = (float*)alloc((size_t)CCAT*CC*4);
  float* WdT      = (float*)alloc((size_t)CC*CD*4);
  float* WeT      = (float*)alloc((size_t)CD*CE*4);
  float* WfT      = (float*)alloc((size_t)CE*CG*4);
  float* partials = (float*)alloc((size_t)(BATCH*NPTS/P)*NGRP*2*4);
  float* stats    = (float*)alloc((size_t)BATCH*NGRP*2*4);
  float* lbase    = (float*)alloc((size_t)BATCH*NPTS*CF*4);
  unsigned* gmaxU  = (unsigned*)alloc((size_t)BATCH*CG*4);
  unsigned* glmaxU = (unsigned*)alloc((size_t)BATCH*CG*4);

  hipMemsetAsync(gmaxU, 0, (size_t)BATCH*CG*4, stream);
  hipMemsetAsync(glmaxU, 0, (size_t)BATCH*CG*4, stream);

  k_pack<<<(CF/16*CF/32*64 + 255)/256, 256, 0, stream>>>(W1, W1p, CF, CF);
  k_pack<<<(CA/16*CF/32*64 + 255)/256, 256, 0, stream>>>(Wa, Wap, CA, CF);
  k_pack<<<(CB/16*CA/32*64 + 255)/256, 256, 0, stream>>>(Wb, Wbp, CB, CA);
  k_transpose<<<(CC*CCAT+255)/256, 256, 0, stream>>>(Wc, WcT, CC, CCAT);
  k_transpose<<<(CD*CC+255)/256, 256, 0, stream>>>(Wd, WdT, CD, CC);
  k_transpose<<<(CE*CD+255)/256, 256, 0, stream>>>(We, WeT, CE, CD);
  k_transpose<<<(CG*CE+255)/256, 256, 0, stream>>>(Wf, WfT, CG, CE);

  k_sq_h<<<(BATCH*NPTS*CH+255)/256, 256, 0, stream>>>(x, f, Wit, bit, h);
  k_knn<<<BATCH*NPTS/4, 256, 0, stream>>>(x, idx);
  k_stats<<<BATCH*NPTS/P, 256, 0, stream>>>(h, idx, W1p, partials);
  k_reduce<<<BATCH*NGRP, 256, 0, stream>>>(partials, stats);
  k_main<<<BATCH*NPTS/P, 256, 0, stream>>>(h, idx, W1p, gng, gnb, stats,
                                           Wap, ba, Wbp, bb, lbase, gmaxU);
  k_tail<<<BATCH*NPTS/TN, 256, 0, stream>>>(lbase, gmaxU, WcT, bc, WdT, bd,
                                            WeT, be, WfT, bf, out, glmaxU);
  k_final<<<(BATCH*CG+255)/256, 256, 0, stream>>>(glmaxU, out);
}

// Round 4
// 384.211 us; speedup vs baseline: 5.1126x; 1.5713x over previous
//
#include <hip/hip_runtime.h>

#define BATCH 8
#define NPTS 2048
#define KNNK 16
#define CH 64
#define CF 128
#define CA 256
#define CB 512
#define CCAT 640
#define CC 256
#define CD 128
#define CE 256
#define CG 512
#define NGRP 4
#define EPSF 1e-5f
#define GF_OFF (BATCH*CG)
#define P 8              // points per MFMA block (k_main)
#define MROWS (P*KNNK)   // 128 rows
#define TM 64            // points per k_tail block

typedef __attribute__((ext_vector_type(8))) short short8v;
typedef __attribute__((ext_vector_type(4))) float f32x4;

__device__ inline short f2bf(float f) {
  union { float f; unsigned u; } v; v.f = f;
  unsigned r = v.u + 0x7fff + ((v.u >> 16) & 1);
  return (short)(r >> 16);
}

// XOR-swizzled LDS element index (bf16 elements; flips 16B slot within 128B)
#define LIDX(r, c, ROW) ((r)*(ROW) + ((c) ^ (((r)&7)<<3)))

// dst[c*R + r] = src[r*C + c]
__global__ void k_transpose(const float* __restrict__ src, float* __restrict__ dst,
                            int R, int C) {
  int i = blockIdx.x * 256 + threadIdx.x;
  if (i < R * C) {
    int r = i / C, c = i - r * C;
    dst[c * R + r] = src[i];
  }
}

// pack W[O][ld] (f32, leading C cols used) into MFMA B-fragment-linear bf16
__global__ void k_pack(const float* __restrict__ W, short* __restrict__ Wp,
                       int O, int C, int ld) {
  int tid = blockIdx.x * 256 + threadIdx.x;
  int KS = C >> 5;
  int total = (O >> 4) * KS * 64;
  if (tid >= total) return;
  int l = tid & 63;
  int fs = tid >> 6;
  int nt = fs / KS, ks = fs - nt * KS;
  int o = nt * 16 + (l & 15);
  int c = ks * 32 + (l >> 4) * 8;
  const float* src = W + (size_t)o * ld + c;
  short8v v;
#pragma unroll
  for (int j = 0; j < 8; ++j) v[j] = f2bf(src[j]);
  *(short8v*)&Wp[(size_t)tid * 8] = v;
}

__global__ void k_sq_h(const float* __restrict__ x, const float* __restrict__ f,
                       const float* __restrict__ Wit, const float* __restrict__ bit,
                       float* __restrict__ h) {
  int t = blockIdx.x * 256 + threadIdx.x;
  if (t >= BATCH * NPTS * CH) return;
  int o = t & (CH - 1);
  int bn = t >> 6;
  int n = bn & (NPTS - 1);
  int b = bn >> 11;
  float f0 = f[(b*3 + 0)*NPTS + n];
  float f1 = f[(b*3 + 1)*NPTS + n];
  float f2 = f[(b*3 + 2)*NPTS + n];
  h[t] = f0*Wit[o*3+0] + f1*Wit[o*3+1] + f2*Wit[o*3+2] + bit[o];
}

// one wave per query; lane owns candidate chunk [32*lane, 32*lane+32)
__global__ __launch_bounds__(256)
void k_knn(const float* __restrict__ x, int* __restrict__ idxout) {
  __shared__ float xs0[2112], xs1[2112], xs2[2112], sqs[2112];
  int blk = blockIdx.x;
  int b = blk >> 9;               // 512 blocks per batch
  int n0 = (blk & 511) * 4;
  int t = threadIdx.x;
  for (int i = t; i < NPTS; i += 256) {
    float x0 = x[(b*3 + 0)*NPTS + i];
    float x1 = x[(b*3 + 1)*NPTS + i];
    float x2 = x[(b*3 + 2)*NPTS + i];
    int a = (i >> 5)*33 + (i & 31);
    xs0[a] = x0; xs1[a] = x1; xs2[a] = x2;
    sqs[a] = __fadd_rn(__fadd_rn(__fmul_rn(x0,x0), __fmul_rn(x1,x1)), __fmul_rn(x2,x2));
  }
  __syncthreads();
  int lane = t & 63, wv = t >> 6;
  int q = n0 + wv;
  int qa = (q >> 5)*33 + (q & 31);
  float qx = xs0[qa], qy = xs1[qa], qz = xs2[qa];
  float sqq = sqs[qa];
  float d[32];
  int base = lane * 32;
#pragma unroll
  for (int jj = 0; jj < 32; ++jj) {
    int a = lane*33 + jj;
    float mx = xs0[a], my = xs1[a], mz = xs2[a];
    float dot = __fadd_rn(__fadd_rn(__fmul_rn(qx,mx), __fmul_rn(qy,my)), __fmul_rn(qz,mz));
    d[jj] = __fsub_rn(__fadd_rn(sqq, sqs[a]), __fadd_rn(dot, dot));
  }
  const float FINF = __builtin_inff();
  float sv0 = d[0]; int si0 = base;
#pragma unroll
  for (int jj = 1; jj < 16; ++jj)
    if (d[jj] < sv0) { sv0 = d[jj]; si0 = base + jj; }
  float sv1 = d[16]; int si1 = base + 16;
#pragma unroll
  for (int jj = 17; jj < 32; ++jj)
    if (d[jj] < sv1) { sv1 = d[jj]; si1 = base + jj; }
  int gsel = 0;
#pragma unroll
  for (int r = 0; r < KNNK; ++r) {
    float v = sv0; int i = si0;
    if (sv1 < v || (sv1 == v && si1 < i)) { v = sv1; i = si1; }
#pragma unroll
    for (int off = 32; off > 0; off >>= 1) {
      float v2 = __shfl_xor(v, off);
      int   i2 = __shfl_xor(i, off);
      if (v2 < v || (v2 == v && i2 < i)) { v = v2; i = i2; }
    }
    if (lane == r) gsel = i;
    int rem = ((i >> 5) == lane) ? (i & 31) : 64;
    if (rem < 16) {
      float nv = FINF; int ni = 0x7fffffff;
#pragma unroll
      for (int jj = 0; jj < 16; ++jj) {
        float dv = (jj == rem) ? FINF : d[jj];
        d[jj] = dv;
        if (dv < nv) { nv = dv; ni = base + jj; }
      }
      sv0 = nv; si0 = ni;
    } else if (rem < 32) {
      float nv = FINF; int ni = 0x7fffffff;
#pragma unroll
      for (int jj = 16; jj < 32; ++jj) {
        float dv = (jj == rem) ? FINF : d[jj];
        d[jj] = dv;
        if (dv < nv) { nv = dv; ni = base + jj; }
      }
      sv1 = nv; si1 = ni;
    }
  }
  if (lane < KNNK) idxout[(size_t)(b*NPTS + q)*KNNK + lane] = gsel;
}

// --- stage 128 edge-feature rows (8 points x 16 nbrs) into swizzled bf16 LDS ---
__device__ inline void stage_feat(short* featS, const float* __restrict__ h,
                                  const int* __restrict__ idx, int b, int n0, int t) {
  int r = t >> 1, cb = (t & 1) * 32;
  int p = r >> 4, kk = r & 15;
  int nbi = idx[(size_t)(b*NPTS + n0 + p)*KNNK + kk];
  const float* hq = h + (size_t)(b*NPTS + n0 + p)*CH;
  const float* hn = h + (size_t)(b*NPTS + nbi)*CH;
#pragma unroll
  for (int j = 0; j < 32; j += 8) {
    float4 q0 = *(const float4*)(hq + cb + j);
    float4 q1 = *(const float4*)(hq + cb + j + 4);
    float4 a0 = *(const float4*)(hn + cb + j);
    float4 a1 = *(const float4*)(hn + cb + j + 4);
    short8v dv, qv;
    dv[0]=f2bf(a0.x-q0.x); dv[1]=f2bf(a0.y-q0.y); dv[2]=f2bf(a0.z-q0.z); dv[3]=f2bf(a0.w-q0.w);
    dv[4]=f2bf(a1.x-q1.x); dv[5]=f2bf(a1.y-q1.y); dv[6]=f2bf(a1.z-q1.z); dv[7]=f2bf(a1.w-q1.w);
    qv[0]=f2bf(q0.x); qv[1]=f2bf(q0.y); qv[2]=f2bf(q0.z); qv[3]=f2bf(q0.w);
    qv[4]=f2bf(q1.x); qv[5]=f2bf(q1.y); qv[6]=f2bf(q1.z); qv[7]=f2bf(q1.w);
    *(short8v*)&featS[LIDX(r, cb + j, CF)] = dv;
    *(short8v*)&featS[LIDX(r, 64 + cb + j, CF)] = qv;
  }
}

// GEMM1 only, accumulate GroupNorm partial sums per (block, group)
__global__ __launch_bounds__(256, 2)
void k_stats(const float* __restrict__ h, const int* __restrict__ idx,
             const short* __restrict__ W1p, float* __restrict__ partials) {
  __shared__ short featS[MROWS*CF];
  int blk = blockIdx.x;
  int b = blk >> 8;
  int n0 = (blk & 255) * P;
  int t = threadIdx.x;
  stage_feat(featS, h, idx, b, n0, t);
  __syncthreads();
  int lane = t & 63, wv = t >> 6;
  int r16 = lane & 15, g8 = (lane >> 4) * 8;
  short8v af[8][4];
#pragma unroll
  for (int m = 0; m < 8; ++m)
#pragma unroll
    for (int ks = 0; ks < 4; ++ks)
      af[m][ks] = *(const short8v*)&featS[LIDX(m*16 + r16, ks*32 + g8, CF)];
  float s = 0.f, ss = 0.f;
#pragma unroll
  for (int n = 0; n < 2; ++n) {
    int nt = 2*wv + n;
    short8v bfr[4];
#pragma unroll
    for (int ks = 0; ks < 4; ++ks)
      bfr[ks] = *(const short8v*)&W1p[(size_t)((nt*4 + ks)*64 + lane)*8];
#pragma unroll
    for (int m = 0; m < 8; ++m) {
      f32x4 acc = {0.f, 0.f, 0.f, 0.f};
#pragma unroll
      for (int ks = 0; ks < 4; ++ks)
        acc = __builtin_amdgcn_mfma_f32_16x16x32_bf16(af[m][ks], bfr[ks], acc, 0, 0, 0);
#pragma unroll
      for (int i = 0; i < 4; ++i) { s += acc[i]; ss += acc[i]*acc[i]; }
    }
  }
#pragma unroll
  for (int off = 32; off > 0; off >>= 1) {
    s += __shfl_xor(s, off);
    ss += __shfl_xor(ss, off);
  }
  if (lane == 0) {
    partials[(size_t)(blk*NGRP + wv)*2 + 0] = s;
    partials[(size_t)(blk*NGRP + wv)*2 + 1] = ss;
  }
}

__global__ void k_reduce(const float* __restrict__ partials, float* __restrict__ stats) {
  int b = blockIdx.x >> 2, g = blockIdx.x & 3;
  int t = threadIdx.x;
  float s  = partials[(size_t)((b*256 + t)*NGRP + g)*2 + 0];
  float ss = partials[(size_t)((b*256 + t)*NGRP + g)*2 + 1];
  __shared__ float rs[256], rss[256];
  rs[t] = s; rss[t] = ss;
  __syncthreads();
  for (int st = 128; st > 0; st >>= 1) {
    if (t < st) { rs[t] += rs[t+st]; rss[t] += rss[t+st]; }
    __syncthreads();
  }
  if (t == 0) {
    const float cnt = (float)((size_t)NPTS * KNNK * 32);
    float mu = rs[0] / cnt;
    float var = rss[0] / cnt - mu*mu;
    stats[(b*NGRP+g)*2+0] = mu;
    stats[(b*NGRP+g)*2+1] = rsqrtf(var + EPSF);
  }
}

__global__ __launch_bounds__(256, 1)
void k_main(const float* __restrict__ h, const int* __restrict__ idx,
            const short* __restrict__ W1p, const float* __restrict__ gng,
            const float* __restrict__ gnb, const float* __restrict__ stats,
            const short* __restrict__ Wap, const float* __restrict__ ba,
            const short* __restrict__ Wbp, const float* __restrict__ bb,
            float* __restrict__ lbase, unsigned* __restrict__ gmaxU) {
  __shared__ short featS[MROWS*CF];   // 32 KB
  __shared__ short ynS[MROWS*CF];     // 32 KB
  __shared__ short g1S[MROWS*CA];     // 64 KB
  int blk = blockIdx.x;
  int b = blk >> 8;
  int n0 = (blk & 255) * P;
  int t = threadIdx.x;
  stage_feat(featS, h, idx, b, n0, t);
  __syncthreads();
  int lane = t & 63, wv = t >> 6;
  int r16 = lane & 15, g8 = (lane >> 4) * 8;
  int rowg = (lane >> 4) * 4;
  // ---- GEMM1: y = feat @ W1^T, GN affine + leaky, -> ynS (bf16) + lbase ----
  {
    short8v af[8][4];
#pragma unroll
    for (int m = 0; m < 8; ++m)
#pragma unroll
      for (int ks = 0; ks < 4; ++ks)
        af[m][ks] = *(const short8v*)&featS[LIDX(m*16 + r16, ks*32 + g8, CF)];
    float mu  = stats[(b*NGRP + wv)*2 + 0];
    float rsg = stats[(b*NGRP + wv)*2 + 1];
#pragma unroll
    for (int n = 0; n < 2; ++n) {
      int nt = 2*wv + n;
      int o = nt*16 + r16;
      short8v bfr[4];
#pragma unroll
      for (int ks = 0; ks < 4; ++ks)
        bfr[ks] = *(const short8v*)&W1p[(size_t)((nt*4 + ks)*64 + lane)*8];
      float ga = gng[o], bev = gnb[o];
#pragma unroll
      for (int m = 0; m < 8; ++m) {
        f32x4 acc = {0.f, 0.f, 0.f, 0.f};
#pragma unroll
        for (int ks = 0; ks < 4; ++ks)
          acc = __builtin_amdgcn_mfma_f32_16x16x32_bf16(af[m][ks], bfr[ks], acc, 0, 0, 0);
        float vmax = -3.0e38f;
#pragma unroll
        for (int i = 0; i < 4; ++i) {
          float v = (acc[i] - mu) * rsg * ga + bev;
          v = (v >= 0.f) ? v : 0.2f*v;
          vmax = fmaxf(vmax, v);
          ynS[LIDX(m*16 + rowg + i, o, CF)] = f2bf(v);
        }
        vmax = fmaxf(vmax, __shfl_xor(vmax, 16));
        vmax = fmaxf(vmax, __shfl_xor(vmax, 32));
        if (lane < 16) lbase[(size_t)(b*NPTS + n0 + m)*CF + o] = vmax;
      }
    }
  }
  __syncthreads();
  // ---- GEMM2: g1 = relu(yn @ Wa^T + ba) -> g1S (bf16) ----
  {
    short8v yf[8][4];
#pragma unroll
    for (int m = 0; m < 8; ++m)
#pragma unroll
      for (int ks = 0; ks < 4; ++ks)
        yf[m][ks] = *(const short8v*)&ynS[LIDX(m*16 + r16, ks*32 + g8, CF)];
#pragma unroll
    for (int nn = 0; nn < 4; ++nn) {
      int nt = wv*4 + nn;
      int o = nt*16 + r16;
      short8v bfr[4];
#pragma unroll
      for (int ks = 0; ks < 4; ++ks)
        bfr[ks] = *(const short8v*)&Wap[(size_t)((nt*4 + ks)*64 + lane)*8];
      float bav = ba[o];
#pragma unroll
      for (int m = 0; m < 8; ++m) {
        f32x4 acc = {0.f, 0.f, 0.f, 0.f};
#pragma unroll
        for (int ks = 0; ks < 4; ++ks)
          acc = __builtin_amdgcn_mfma_f32_16x16x32_bf16(yf[m][ks], bfr[ks], acc, 0, 0, 0);
#pragma unroll
        for (int i = 0; i < 4; ++i) {
          float v = fmaxf(acc[i] + bav, 0.f);
          g1S[LIDX(m*16 + rowg + i, o, CA)] = f2bf(v);
        }
      }
    }
  }
  __syncthreads();
  // ---- GEMM3: g2 = g1 @ Wb^T + bb, max over k & points, atomicMax over n ----
  {
    short8v gf[8][8];
#pragma unroll
    for (int m = 0; m < 8; ++m)
#pragma unroll
      for (int ks = 0; ks < 8; ++ks)
        gf[m][ks] = *(const short8v*)&g1S[LIDX(m*16 + r16, ks*32 + g8, CA)];
#pragma unroll
    for (int nn = 0; nn < 8; ++nn) {
      int nt = wv*8 + nn;
      short8v bfr[8];
#pragma unroll
      for (int ks = 0; ks < 8; ++ks)
        bfr[ks] = *(const short8v*)&Wbp[(size_t)((nt*8 + ks)*64 + lane)*8];
      f32x4 acc[8];
#pragma unroll
      for (int m = 0; m < 8; ++m) acc[m] = (f32x4){0.f, 0.f, 0.f, 0.f};
#pragma unroll
      for (int ks = 0; ks < 8; ++ks)
#pragma unroll
        for (int m = 0; m < 8; ++m)
          acc[m] = __builtin_amdgcn_mfma_f32_16x16x32_bf16(gf[m][ks], bfr[ks], acc[m], 0, 0, 0);
      float b0 = bb[nt*16 + r16];
      float am = 0.f;  // relu fold
#pragma unroll
      for (int m = 0; m < 8; ++m)
#pragma unroll
        for (int i = 0; i < 4; ++i) am = fmaxf(am, acc[m][i] + b0);
      am = fmaxf(am, __shfl_xor(am, 16));
      am = fmaxf(am, __shfl_xor(am, 32));
      if (lane < 16) atomicMax(&gmaxU[b*CG + nt*16 + lane], __float_as_uint(am));
    }
  }
}

// per-batch effective bias: bceff[b][o] = bc[o] + sum_c gmax[b][c]*Wc[o][128+c]
__global__ void k_gbias(const unsigned* __restrict__ gmaxU, const float* __restrict__ WcT,
                        const float* __restrict__ bc, float* __restrict__ bceff) {
  int b = blockIdx.x;
  int o = threadIdx.x;   // 256
  float acc = bc[o];
  for (int c = 0; c < CB; ++c)
    acc += __uint_as_float(gmaxU[b*CG + c]) * WcT[(size_t)(CF + c)*CC + o];
  bceff[b*CC + o] = acc;
}

// MFMA tail: lf1=relu(lbase@WcL^T+bceff); lf2=relu(lf1@Wd^T+bd)->out;
// gl1=relu(lf2@We^T+be); gl2 max -> glmaxU
__global__ __launch_bounds__(256)
void k_tail(const float* __restrict__ lbase, const float* __restrict__ bceff,
            const short* __restrict__ WcLp,
            const short* __restrict__ Wdp, const float* __restrict__ bd,
            const short* __restrict__ Wep, const float* __restrict__ be,
            const short* __restrict__ Wfp, const float* __restrict__ bf,
            float* __restrict__ out, unsigned* __restrict__ glmaxU) {
  __shared__ short aS0[TM*CF];   // 16 KB: lbase, then lf2
  __shared__ short aS1[TM*CA];   // 32 KB: lf1, then gl1
  int blk = blockIdx.x;
  int b = blk >> 5;              // 32 blocks per batch
  int n0 = (blk & 31) * TM;
  int t = threadIdx.x;
  // stage lbase (f32 -> bf16, swizzled)
  {
    int r = t >> 2, cb = (t & 3) * 32;
    const float* src = lbase + (size_t)(b*NPTS + n0 + r)*CF + cb;
#pragma unroll
    for (int j = 0; j < 32; j += 8) {
      float4 v0 = *(const float4*)(src + j);
      float4 v1 = *(const float4*)(src + j + 4);
      short8v pv;
      pv[0]=f2bf(v0.x); pv[1]=f2bf(v0.y); pv[2]=f2bf(v0.z); pv[3]=f2bf(v0.w);
      pv[4]=f2bf(v1.x); pv[5]=f2bf(v1.y); pv[6]=f2bf(v1.z); pv[7]=f2bf(v1.w);
      *(short8v*)&aS0[LIDX(r, cb + j, CF)] = pv;
    }
  }
  __syncthreads();
  int lane = t & 63, wv = t >> 6;
  int r16 = lane & 15, g8 = (lane >> 4) * 8;
  int rowg = (lane >> 4) * 4;
  // ---- GEMM-c: lf1 = relu(aS0 @ WcL^T + bceff) -> aS1 ----
  {
    short8v af[4][4];
#pragma unroll
    for (int mt = 0; mt < 4; ++mt)
#pragma unroll
      for (int ks = 0; ks < 4; ++ks)
        af[mt][ks] = *(const short8v*)&aS0[LIDX(mt*16 + r16, ks*32 + g8, CF)];
#pragma unroll
    for (int nn = 0; nn < 4; ++nn) {
      int nt = wv*4 + nn;
      int o = nt*16 + r16;
      short8v bfr[4];
#pragma unroll
      for (int ks = 0; ks < 4; ++ks)
        bfr[ks] = *(const short8v*)&WcLp[(size_t)((nt*4 + ks)*64 + lane)*8];
      float bce = bceff[b*CC + o];
#pragma unroll
      for (int mt = 0; mt < 4; ++mt) {
        f32x4 acc = {0.f, 0.f, 0.f, 0.f};
#pragma unroll
        for (int ks = 0; ks < 4; ++ks)
          acc = __builtin_amdgcn_mfma_f32_16x16x32_bf16(af[mt][ks], bfr[ks], acc, 0, 0, 0);
#pragma unroll
        for (int i = 0; i < 4; ++i)
          aS1[LIDX(mt*16 + rowg + i, o, CA)] = f2bf(fmaxf(acc[i] + bce, 0.f));
      }
    }
  }
  __syncthreads();
  // ---- GEMM-d: lf2 = relu(aS1 @ Wd^T + bd) -> aS0 + global local_feat ----
  {
    short8v af[4][8];
#pragma unroll
    for (int mt = 0; mt < 4; ++mt)
#pragma unroll
      for (int ks = 0; ks < 8; ++ks)
        af[mt][ks] = *(const short8v*)&aS1[LIDX(mt*16 + r16, ks*32 + g8, CA)];
#pragma unroll
    for (int nn = 0; nn < 2; ++nn) {
      int nt = wv*2 + nn;
      int o = nt*16 + r16;
      short8v bfr[8];
#pragma unroll
      for (int ks = 0; ks < 8; ++ks)
        bfr[ks] = *(const short8v*)&Wdp[(size_t)((nt*8 + ks)*64 + lane)*8];
      float bdv = bd[o];
#pragma unroll
      for (int mt = 0; mt < 4; ++mt) {
        f32x4 acc = {0.f, 0.f, 0.f, 0.f};
#pragma unroll
        for (int ks = 0; ks < 8; ++ks)
          acc = __builtin_amdgcn_mfma_f32_16x16x32_bf16(af[mt][ks], bfr[ks], acc, 0, 0, 0);
#pragma unroll
        for (int i = 0; i < 4; ++i) {
          float v = fmaxf(acc[i] + bdv, 0.f);
          aS0[LIDX(mt*16 + rowg + i, o, CF)] = f2bf(v);
          out[GF_OFF + ((size_t)(b*CD + o))*NPTS + n0 + mt*16 + rowg + i] = v;
        }
      }
    }
  }
  __syncthreads();
  // ---- GEMM-e: gl1 = relu(aS0 @ We^T + be) -> aS1 ----
  {
    short8v af[4][4];
#pragma unroll
    for (int mt = 0; mt < 4; ++mt)
#pragma unroll
      for (int ks = 0; ks < 4; ++ks)
        af[mt][ks] = *(const short8v*)&aS0[LIDX(mt*16 + r16, ks*32 + g8, CF)];
#pragma unroll
    for (int nn = 0; nn < 4; ++nn) {
      int nt = wv*4 + nn;
      int o = nt*16 + r16;
      short8v bfr[4];
#pragma unroll
      for (int ks = 0; ks < 4; ++ks)
        bfr[ks] = *(const short8v*)&Wep[(size_t)((nt*4 + ks)*64 + lane)*8];
      float bev = be[o];
#pragma unroll
      for (int mt = 0; mt < 4; ++mt) {
        f32x4 acc = {0.f, 0.f, 0.f, 0.f};
#pragma unroll
        for (int ks = 0; ks < 4; ++ks)
          acc = __builtin_amdgcn_mfma_f32_16x16x32_bf16(af[mt][ks], bfr[ks], acc, 0, 0, 0);
#pragma unroll
        for (int i = 0; i < 4; ++i)
          aS1[LIDX(mt*16 + rowg + i, o, CA)] = f2bf(fmaxf(acc[i] + bev, 0.f));
      }
    }
  }
  __syncthreads();
  // ---- GEMM-f: gl2 = gl1 @ Wf^T + bf, relu+max over rows, atomicMax over n ----
  {
    short8v af[4][8];
#pragma unroll
    for (int mt = 0; mt < 4; ++mt)
#pragma unroll
      for (int ks = 0; ks < 8; ++ks)
        af[mt][ks] = *(const short8v*)&aS1[LIDX(mt*16 + r16, ks*32 + g8, CA)];
#pragma unroll
    for (int nn = 0; nn < 8; ++nn) {
      int nt = wv*8 + nn;
      short8v bfr[8];
#pragma unroll
      for (int ks = 0; ks < 8; ++ks)
        bfr[ks] = *(const short8v*)&Wfp[(size_t)((nt*8 + ks)*64 + lane)*8];
      float bfv = bf[nt*16 + r16];
      float am = 0.f;  // relu fold
#pragma unroll
      for (int mt = 0; mt < 4; ++mt) {
        f32x4 acc = {0.f, 0.f, 0.f, 0.f};
#pragma unroll
        for (int ks = 0; ks < 8; ++ks)
          acc = __builtin_amdgcn_mfma_f32_16x16x32_bf16(af[mt][ks], bfr[ks], acc, 0, 0, 0);
#pragma unroll
        for (int i = 0; i < 4; ++i) am = fmaxf(am, acc[i] + bfv);
      }
      am = fmaxf(am, __shfl_xor(am, 16));
      am = fmaxf(am, __shfl_xor(am, 32));
      if (lane < 16) atomicMax(&glmaxU[b*CG + nt*16 + lane], __float_as_uint(am));
    }
  }
}

__global__ void k_final(const unsigned* __restrict__ glmaxU, float* __restrict__ out) {
  int i = blockIdx.x*256 + threadIdx.x;
  if (i < BATCH*CG) out[i] = __uint_as_float(glmaxU[i]);
}

extern "C" void kernel_launch(void* const* d_in, const int* in_sizes, int n_in,
                              void* d_out, int out_size, void* d_ws, size_t ws_size,
                              hipStream_t stream) {
  const float* x   = (const float*)d_in[0];
  const float* f   = (const float*)d_in[1];
  const float* Wit = (const float*)d_in[2];
  const float* bit = (const float*)d_in[3];
  const float* W1  = (const float*)d_in[4];
  const float* gng = (const float*)d_in[5];
  const float* gnb = (const float*)d_in[6];
  const float* Wa  = (const float*)d_in[7];
  const float* ba  = (const float*)d_in[8];
  const float* Wb  = (const float*)d_in[9];
  const float* bb  = (const float*)d_in[10];
  const float* Wc  = (const float*)d_in[11];
  const float* bc  = (const float*)d_in[12];
  const float* Wd  = (const float*)d_in[13];
  const float* bd  = (const float*)d_in[14];
  const float* We  = (const float*)d_in[15];
  const float* be  = (const float*)d_in[16];
  const float* Wf  = (const float*)d_in[17];
  const float* bf  = (const float*)d_in[18];
  float* out = (float*)d_out;

  char* w = (char*)d_ws;
  size_t off = 0;
  auto alloc = [&](size_t bytes) {
    void* p = w + off; off += (bytes + 255) & ~(size_t)255; return p;
  };
  float* h        = (float*)alloc((size_t)BATCH*NPTS*CH*4);
  int*   idx      = (int*)  alloc((size_t)BATCH*NPTS*KNNK*4);
  short* W1p      = (short*)alloc((size_t)CF*CF*2);
  short* Wap      = (short*)alloc((size_t)CA*CF*2);
  short* Wbp      = (short*)alloc((size_t)CB*CA*2);
  short* WcLp     = (short*)alloc((size_t)CC*CF*2);
  short* Wdp      = (short*)alloc((size_t)CD*CC*2);
  short* Wep      = (short*)alloc((size_t)CE*CD*2);
  short* Wfp      = (short*)alloc((size_t)CG*CE*2);
  float* WcT      = (float*)alloc((size_t)CCAT*CC*4);
  float* bceff    = (float*)alloc((size_t)BATCH*CC*4);
  float* partials = (float*)alloc((size_t)(BATCH*NPTS/P)*NGRP*2*4);
  float* stats    = (float*)alloc((size_t)BATCH*NGRP*2*4);
  float* lbase    = (float*)alloc((size_t)BATCH*NPTS*CF*4);
  unsigned* gmaxU  = (unsigned*)alloc((size_t)BATCH*CG*4);
  unsigned* glmaxU = (unsigned*)alloc((size_t)BATCH*CG*4);

  hipMemsetAsync(gmaxU, 0, (size_t)BATCH*CG*4, stream);
  hipMemsetAsync(glmaxU, 0, (size_t)BATCH*CG*4, stream);

  k_pack<<<8,  256, 0, stream>>>(W1, W1p, CF, CF, CF);
  k_pack<<<16, 256, 0, stream>>>(Wa, Wap, CA, CF, CF);
  k_pack<<<64, 256, 0, stream>>>(Wb, Wbp, CB, CA, CA);
  k_pack<<<16, 256, 0, stream>>>(Wc, WcLp, CC, CF, CCAT);
  k_pack<<<16, 256, 0, stream>>>(Wd, Wdp, CD, CC, CC);
  k_pack<<<16, 256, 0, stream>>>(We, Wep, CE, CD, CD);
  k_pack<<<64, 256, 0, stream>>>(Wf, Wfp, CG, CE, CE);
  k_transpose<<<(CC*CCAT+255)/256, 256, 0, stream>>>(Wc, WcT, CC, CCAT);

  k_sq_h<<<(BATCH*NPTS*CH+255)/256, 256, 0, stream>>>(x, f, Wit, bit, h);
  k_knn<<<BATCH*NPTS/4, 256, 0, stream>>>(x, idx);
  k_stats<<<BATCH*NPTS/P, 256, 0, stream>>>(h, idx, W1p, partials);
  k_reduce<<<BATCH*NGRP, 256, 0, stream>>>(partials, stats);
  k_main<<<BATCH*NPTS/P, 256, 0, stream>>>(h, idx, W1p, gng, gnb, stats,
                                           Wap, ba, Wbp, bb, lbase, gmaxU);
  k_gbias<<<BATCH, 256, 0, stream>>>(gmaxU, WcT, bc, bceff);
  k_tail<<<BATCH*NPTS/TM, 256, 0, stream>>>(lbase, bceff, WcLp, Wdp, bd,
                                            Wep, be, Wfp, bf, out, glmaxU);
  k_final<<<(BATCH*CG+255)/256, 256, 0, stream>>>(glmaxU, out);
}

// Round 5
// 300.762 us; speedup vs baseline: 6.5311x; 1.2775x over previous
//
#include <hip/hip_runtime.h>

#define BATCH 8
#define NPTS 2048
#define KNNK 16
#define CH 64
#define CF 128
#define CA 256
#define CB 512
#define CCAT 640
#define CC 256
#define CD 128
#define CE 256
#define CG 512
#define NGRP 4
#define EPSF 1e-5f
#define GF_OFF (BATCH*CG)
#define P 8              // points per MFMA block (k_main)
#define MROWS (P*KNNK)   // 128 rows
#define TM 64            // points per k_tail block

typedef __attribute__((ext_vector_type(8))) short short8v;
typedef __attribute__((ext_vector_type(4))) float f32x4;

__device__ inline short f2bf(float f) {
  union { float f; unsigned u; } v; v.f = f;
  unsigned r = v.u + 0x7fff + ((v.u >> 16) & 1);
  return (short)(r >> 16);
}

// XOR-swizzled LDS element index (bf16 elements; flips 16B slot within 128B)
#define LIDX(r, c, ROW) ((r)*(ROW) + ((c) ^ (((r)&7)<<3)))

// dst[c*R + r] = src[r*C + c]
__global__ void k_transpose(const float* __restrict__ src, float* __restrict__ dst,
                            int R, int C) {
  int i = blockIdx.x * 256 + threadIdx.x;
  if (i < R * C) {
    int r = i / C, c = i - r * C;
    dst[c * R + r] = src[i];
  }
}

// pack W[O][ld] (f32, leading C cols used) into MFMA B-fragment-linear bf16
__global__ void k_pack(const float* __restrict__ W, short* __restrict__ Wp,
                       int O, int C, int ld) {
  int tid = blockIdx.x * 256 + threadIdx.x;
  int KS = C >> 5;
  int total = (O >> 4) * KS * 64;
  if (tid >= total) return;
  int l = tid & 63;
  int fs = tid >> 6;
  int nt = fs / KS, ks = fs - nt * KS;
  int o = nt * 16 + (l & 15);
  int c = ks * 32 + (l >> 4) * 8;
  const float* src = W + (size_t)o * ld + c;
  short8v v;
#pragma unroll
  for (int j = 0; j < 8; ++j) v[j] = f2bf(src[j]);
  *(short8v*)&Wp[(size_t)tid * 8] = v;
}

__global__ void k_sq_h(const float* __restrict__ x, const float* __restrict__ f,
                       const float* __restrict__ Wit, const float* __restrict__ bit,
                       float* __restrict__ h) {
  int t = blockIdx.x * 256 + threadIdx.x;
  if (t >= BATCH * NPTS * CH) return;
  int o = t & (CH - 1);
  int bn = t >> 6;
  int n = bn & (NPTS - 1);
  int b = bn >> 11;
  float f0 = f[(b*3 + 0)*NPTS + n];
  float f1 = f[(b*3 + 1)*NPTS + n];
  float f2 = f[(b*3 + 2)*NPTS + n];
  h[t] = f0*Wit[o*3+0] + f1*Wit[o*3+1] + f2*Wit[o*3+2] + bit[o];
}

// one wave per query; lane owns candidate chunk [32*lane, 32*lane+32)
__global__ __launch_bounds__(256)
void k_knn(const float* __restrict__ x, int* __restrict__ idxout) {
  __shared__ float xs0[2112], xs1[2112], xs2[2112], sqs[2112];
  int blk = blockIdx.x;
  int b = blk >> 9;               // 512 blocks per batch
  int n0 = (blk & 511) * 4;
  int t = threadIdx.x;
  for (int i = t; i < NPTS; i += 256) {
    float x0 = x[(b*3 + 0)*NPTS + i];
    float x1 = x[(b*3 + 1)*NPTS + i];
    float x2 = x[(b*3 + 2)*NPTS + i];
    int a = (i >> 5)*33 + (i & 31);
    xs0[a] = x0; xs1[a] = x1; xs2[a] = x2;
    sqs[a] = __fadd_rn(__fadd_rn(__fmul_rn(x0,x0), __fmul_rn(x1,x1)), __fmul_rn(x2,x2));
  }
  __syncthreads();
  int lane = t & 63, wv = t >> 6;
  int q = n0 + wv;
  int qa = (q >> 5)*33 + (q & 31);
  float qx = xs0[qa], qy = xs1[qa], qz = xs2[qa];
  float sqq = sqs[qa];
  float d[32];
  int base = lane * 32;
#pragma unroll
  for (int jj = 0; jj < 32; ++jj) {
    int a = lane*33 + jj;
    float mx = xs0[a], my = xs1[a], mz = xs2[a];
    float dot = __fadd_rn(__fadd_rn(__fmul_rn(qx,mx), __fmul_rn(qy,my)), __fmul_rn(qz,mz));
    d[jj] = __fsub_rn(__fadd_rn(sqq, sqs[a]), __fadd_rn(dot, dot));
  }
  const float FINF = __builtin_inff();
  float sv0 = d[0]; int si0 = base;
#pragma unroll
  for (int jj = 1; jj < 16; ++jj)
    if (d[jj] < sv0) { sv0 = d[jj]; si0 = base + jj; }
  float sv1 = d[16]; int si1 = base + 16;
#pragma unroll
  for (int jj = 17; jj < 32; ++jj)
    if (d[jj] < sv1) { sv1 = d[jj]; si1 = base + jj; }
  int gsel = 0;
#pragma unroll
  for (int r = 0; r < KNNK; ++r) {
    float v = sv0; int i = si0;
    if (sv1 < v || (sv1 == v && si1 < i)) { v = sv1; i = si1; }
#pragma unroll
    for (int off = 32; off > 0; off >>= 1) {
      float v2 = __shfl_xor(v, off);
      int   i2 = __shfl_xor(i, off);
      if (v2 < v || (v2 == v && i2 < i)) { v = v2; i = i2; }
    }
    if (lane == r) gsel = i;
    int rem = ((i >> 5) == lane) ? (i & 31) : 64;
    if (rem < 16) {
      float nv = FINF; int ni = 0x7fffffff;
#pragma unroll
      for (int jj = 0; jj < 16; ++jj) {
        float dv = (jj == rem) ? FINF : d[jj];
        d[jj] = dv;
        if (dv < nv) { nv = dv; ni = base + jj; }
      }
      sv0 = nv; si0 = ni;
    } else if (rem < 32) {
      float nv = FINF; int ni = 0x7fffffff;
#pragma unroll
      for (int jj = 16; jj < 32; ++jj) {
        float dv = (jj == rem) ? FINF : d[jj];
        d[jj] = dv;
        if (dv < nv) { nv = dv; ni = base + jj; }
      }
      sv1 = nv; si1 = ni;
    }
  }
  if (lane < KNNK) idxout[(size_t)(b*NPTS + q)*KNNK + lane] = gsel;
}

// --- stage 128 edge-feature rows (8 points x 16 nbrs) into swizzled bf16 LDS ---
__device__ inline void stage_feat(short* featS, const float* __restrict__ h,
                                  const int* __restrict__ idx, int b, int n0, int t) {
  int r = t >> 1, cb = (t & 1) * 32;
  int p = r >> 4, kk = r & 15;
  int nbi = idx[(size_t)(b*NPTS + n0 + p)*KNNK + kk];
  const float* hq = h + (size_t)(b*NPTS + n0 + p)*CH;
  const float* hn = h + (size_t)(b*NPTS + nbi)*CH;
#pragma unroll
  for (int j = 0; j < 32; j += 8) {
    float4 q0 = *(const float4*)(hq + cb + j);
    float4 q1 = *(const float4*)(hq + cb + j + 4);
    float4 a0 = *(const float4*)(hn + cb + j);
    float4 a1 = *(const float4*)(hn + cb + j + 4);
    short8v dv, qv;
    dv[0]=f2bf(a0.x-q0.x); dv[1]=f2bf(a0.y-q0.y); dv[2]=f2bf(a0.z-q0.z); dv[3]=f2bf(a0.w-q0.w);
    dv[4]=f2bf(a1.x-q1.x); dv[5]=f2bf(a1.y-q1.y); dv[6]=f2bf(a1.z-q1.z); dv[7]=f2bf(a1.w-q1.w);
    qv[0]=f2bf(q0.x); qv[1]=f2bf(q0.y); qv[2]=f2bf(q0.z); qv[3]=f2bf(q0.w);
    qv[4]=f2bf(q1.x); qv[5]=f2bf(q1.y); qv[6]=f2bf(q1.z); qv[7]=f2bf(q1.w);
    *(short8v*)&featS[LIDX(r, cb + j, CF)] = dv;
    *(short8v*)&featS[LIDX(r, 64 + cb + j, CF)] = qv;
  }
}

// GEMM1 only, accumulate GroupNorm partial sums per (block, group)
__global__ __launch_bounds__(256, 2)
void k_stats(const float* __restrict__ h, const int* __restrict__ idx,
             const short* __restrict__ W1p, float* __restrict__ partials) {
  __shared__ short featS[MROWS*CF];
  int blk = blockIdx.x;
  int b = blk >> 8;
  int n0 = (blk & 255) * P;
  int t = threadIdx.x;
  stage_feat(featS, h, idx, b, n0, t);
  __syncthreads();
  int lane = t & 63, wv = t >> 6;
  int r16 = lane & 15, g8 = (lane >> 4) * 8;
  short8v af[8][4];
#pragma unroll
  for (int m = 0; m < 8; ++m)
#pragma unroll
    for (int ks = 0; ks < 4; ++ks)
      af[m][ks] = *(const short8v*)&featS[LIDX(m*16 + r16, ks*32 + g8, CF)];
  float s = 0.f, ss = 0.f;
#pragma unroll
  for (int n = 0; n < 2; ++n) {
    int nt = 2*wv + n;
    short8v bfr[4];
#pragma unroll
    for (int ks = 0; ks < 4; ++ks)
      bfr[ks] = *(const short8v*)&W1p[(size_t)((nt*4 + ks)*64 + lane)*8];
#pragma unroll
    for (int m = 0; m < 8; ++m) {
      f32x4 acc = {0.f, 0.f, 0.f, 0.f};
#pragma unroll
      for (int ks = 0; ks < 4; ++ks)
        acc = __builtin_amdgcn_mfma_f32_16x16x32_bf16(af[m][ks], bfr[ks], acc, 0, 0, 0);
#pragma unroll
      for (int i = 0; i < 4; ++i) { s += acc[i]; ss += acc[i]*acc[i]; }
    }
  }
#pragma unroll
  for (int off = 32; off > 0; off >>= 1) {
    s += __shfl_xor(s, off);
    ss += __shfl_xor(ss, off);
  }
  if (lane == 0) {
    partials[(size_t)(blk*NGRP + wv)*2 + 0] = s;
    partials[(size_t)(blk*NGRP + wv)*2 + 1] = ss;
  }
}

__global__ void k_reduce(const float* __restrict__ partials, float* __restrict__ stats) {
  int b = blockIdx.x >> 2, g = blockIdx.x & 3;
  int t = threadIdx.x;
  float s  = partials[(size_t)((b*256 + t)*NGRP + g)*2 + 0];
  float ss = partials[(size_t)((b*256 + t)*NGRP + g)*2 + 1];
  __shared__ float rs[256], rss[256];
  rs[t] = s; rss[t] = ss;
  __syncthreads();
  for (int st = 128; st > 0; st >>= 1) {
    if (t < st) { rs[t] += rs[t+st]; rss[t] += rss[t+st]; }
    __syncthreads();
  }
  if (t == 0) {
    const float cnt = (float)((size_t)NPTS * KNNK * 32);
    float mu = rs[0] / cnt;
    float var = rss[0] / cnt - mu*mu;
    stats[(b*NGRP+g)*2+0] = mu;
    stats[(b*NGRP+g)*2+1] = rsqrtf(var + EPSF);
  }
}

// LDS aliasing: featS [0,32K) + ynS [32K,64K); g1S overlays [0,64K)
__global__ __launch_bounds__(256, 2)
void k_main(const float* __restrict__ h, const int* __restrict__ idx,
            const short* __restrict__ W1p, const float* __restrict__ gng,
            const float* __restrict__ gnb, const float* __restrict__ stats,
            const short* __restrict__ Wap, const float* __restrict__ ba,
            const short* __restrict__ Wbp, const float* __restrict__ bb,
            float* __restrict__ lbase, unsigned* __restrict__ gmaxU) {
  __shared__ short lds[MROWS*CA];     // 64 KB total
  short* featS = lds;                 // 32 KB
  short* ynS   = lds + MROWS*CF;      // 32 KB
  short* g1S   = lds;                 // 64 KB (overlays feat+yn)
  int blk = blockIdx.x;
  int b = blk >> 8;
  int n0 = (blk & 255) * P;
  int t = threadIdx.x;
  stage_feat(featS, h, idx, b, n0, t);
  __syncthreads();
  int lane = t & 63, wv = t >> 6;
  int r16 = lane & 15, g8 = (lane >> 4) * 8;
  int rowg = (lane >> 4) * 4;
  // ---- GEMM1: y = feat @ W1^T, GN affine + leaky, -> ynS (bf16) + lbase ----
  {
    short8v af[8][4];
#pragma unroll
    for (int m = 0; m < 8; ++m)
#pragma unroll
      for (int ks = 0; ks < 4; ++ks)
        af[m][ks] = *(const short8v*)&featS[LIDX(m*16 + r16, ks*32 + g8, CF)];
    float mu  = stats[(b*NGRP + wv)*2 + 0];
    float rsg = stats[(b*NGRP + wv)*2 + 1];
#pragma unroll
    for (int n = 0; n < 2; ++n) {
      int nt = 2*wv + n;
      int o = nt*16 + r16;
      short8v bfr[4];
#pragma unroll
      for (int ks = 0; ks < 4; ++ks)
        bfr[ks] = *(const short8v*)&W1p[(size_t)((nt*4 + ks)*64 + lane)*8];
      float ga = gng[o], bev = gnb[o];
#pragma unroll
      for (int m = 0; m < 8; ++m) {
        f32x4 acc = {0.f, 0.f, 0.f, 0.f};
#pragma unroll
        for (int ks = 0; ks < 4; ++ks)
          acc = __builtin_amdgcn_mfma_f32_16x16x32_bf16(af[m][ks], bfr[ks], acc, 0, 0, 0);
        float vmax = -3.0e38f;
#pragma unroll
        for (int i = 0; i < 4; ++i) {
          float v = (acc[i] - mu) * rsg * ga + bev;
          v = (v >= 0.f) ? v : 0.2f*v;
          vmax = fmaxf(vmax, v);
          ynS[LIDX(m*16 + rowg + i, o, CF)] = f2bf(v);
        }
        vmax = fmaxf(vmax, __shfl_xor(vmax, 16));
        vmax = fmaxf(vmax, __shfl_xor(vmax, 32));
        if (lane < 16) lbase[(size_t)(b*NPTS + n0 + m)*CF + o] = vmax;
      }
    }
  }
  __syncthreads();
  // ---- GEMM2: g1 = relu(yn @ Wa^T + ba) -> g1S (bf16, overlays feat/yn) ----
  {
    short8v yf[8][4];
#pragma unroll
    for (int m = 0; m < 8; ++m)
#pragma unroll
      for (int ks = 0; ks < 4; ++ks)
        yf[m][ks] = *(const short8v*)&ynS[LIDX(m*16 + r16, ks*32 + g8, CF)];
    __syncthreads();   // all waves have yn in regs before overlay write
#pragma unroll
    for (int nn = 0; nn < 4; ++nn) {
      int nt = wv*4 + nn;
      int o = nt*16 + r16;
      short8v bfr[4];
#pragma unroll
      for (int ks = 0; ks < 4; ++ks)
        bfr[ks] = *(const short8v*)&Wap[(size_t)((nt*4 + ks)*64 + lane)*8];
      float bav = ba[o];
#pragma unroll
      for (int m = 0; m < 8; ++m) {
        f32x4 acc = {0.f, 0.f, 0.f, 0.f};
#pragma unroll
        for (int ks = 0; ks < 4; ++ks)
          acc = __builtin_amdgcn_mfma_f32_16x16x32_bf16(yf[m][ks], bfr[ks], acc, 0, 0, 0);
#pragma unroll
        for (int i = 0; i < 4; ++i) {
          float v = fmaxf(acc[i] + bav, 0.f);
          g1S[LIDX(m*16 + rowg + i, o, CA)] = f2bf(v);
        }
      }
    }
  }
  __syncthreads();
  // ---- GEMM3: ks-outer, 2 passes of 4 nt; acc[4][8] stays register-resident ----
#pragma unroll
  for (int half = 0; half < 2; ++half) {
    f32x4 acc[4][8];
#pragma unroll
    for (int nn = 0; nn < 4; ++nn)
#pragma unroll
      for (int m = 0; m < 8; ++m) acc[nn][m] = (f32x4){0.f, 0.f, 0.f, 0.f};
#pragma unroll
    for (int ks = 0; ks < 8; ++ks) {
      short8v gfk[8];
#pragma unroll
      for (int m = 0; m < 8; ++m)
        gfk[m] = *(const short8v*)&g1S[LIDX(m*16 + r16, ks*32 + g8, CA)];
#pragma unroll
      for (int nn = 0; nn < 4; ++nn) {
        int nt = wv*8 + half*4 + nn;
        short8v bfr = *(const short8v*)&Wbp[(size_t)((nt*8 + ks)*64 + lane)*8];
#pragma unroll
        for (int m = 0; m < 8; ++m)
          acc[nn][m] = __builtin_amdgcn_mfma_f32_16x16x32_bf16(gfk[m], bfr, acc[nn][m], 0, 0, 0);
      }
    }
#pragma unroll
    for (int nn = 0; nn < 4; ++nn) {
      int nt = wv*8 + half*4 + nn;
      float b0 = bb[nt*16 + r16];
      float am = 0.f;  // relu fold
#pragma unroll
      for (int m = 0; m < 8; ++m)
#pragma unroll
        for (int i = 0; i < 4; ++i) am = fmaxf(am, acc[nn][m][i] + b0);
      am = fmaxf(am, __shfl_xor(am, 16));
      am = fmaxf(am, __shfl_xor(am, 32));
      if (lane < 16) atomicMax(&gmaxU[b*CG + nt*16 + lane], __float_as_uint(am));
    }
  }
}

// per-batch effective bias: bceff[b][o] = bc[o] + sum_c gmax[b][c]*Wc[o][128+c]
__global__ void k_gbias(const unsigned* __restrict__ gmaxU, const float* __restrict__ WcT,
                        const float* __restrict__ bc, float* __restrict__ bceff) {
  int b = blockIdx.x;
  int o = threadIdx.x;   // 256
  float acc = bc[o];
  for (int c = 0; c < CB; ++c)
    acc += __uint_as_float(gmaxU[b*CG + c]) * WcT[(size_t)(CF + c)*CC + o];
  bceff[b*CC + o] = acc;
}

// MFMA tail: lf1=relu(lbase@WcL^T+bceff); lf2=relu(lf1@Wd^T+bd)->out;
// gl1=relu(lf2@We^T+be); gl2 max -> glmaxU
__global__ __launch_bounds__(256)
void k_tail(const float* __restrict__ lbase, const float* __restrict__ bceff,
            const short* __restrict__ WcLp,
            const short* __restrict__ Wdp, const float* __restrict__ bd,
            const short* __restrict__ Wep, const float* __restrict__ be,
            const short* __restrict__ Wfp, const float* __restrict__ bf,
            float* __restrict__ out, unsigned* __restrict__ glmaxU) {
  __shared__ short aS0[TM*CF];   // 16 KB: lbase, then lf2
  __shared__ short aS1[TM*CA];   // 32 KB: lf1, then gl1
  int blk = blockIdx.x;
  int b = blk >> 5;              // 32 blocks per batch
  int n0 = (blk & 31) * TM;
  int t = threadIdx.x;
  // stage lbase (f32 -> bf16, swizzled)
  {
    int r = t >> 2, cb = (t & 3) * 32;
    const float* src = lbase + (size_t)(b*NPTS + n0 + r)*CF + cb;
#pragma unroll
    for (int j = 0; j < 32; j += 8) {
      float4 v0 = *(const float4*)(src + j);
      float4 v1 = *(const float4*)(src + j + 4);
      short8v pv;
      pv[0]=f2bf(v0.x); pv[1]=f2bf(v0.y); pv[2]=f2bf(v0.z); pv[3]=f2bf(v0.w);
      pv[4]=f2bf(v1.x); pv[5]=f2bf(v1.y); pv[6]=f2bf(v1.z); pv[7]=f2bf(v1.w);
      *(short8v*)&aS0[LIDX(r, cb + j, CF)] = pv;
    }
  }
  __syncthreads();
  int lane = t & 63, wv = t >> 6;
  int r16 = lane & 15, g8 = (lane >> 4) * 8;
  int rowg = (lane >> 4) * 4;
  // ---- GEMM-c: lf1 = relu(aS0 @ WcL^T + bceff) -> aS1 ----
  {
    short8v af[4][4];
#pragma unroll
    for (int mt = 0; mt < 4; ++mt)
#pragma unroll
      for (int ks = 0; ks < 4; ++ks)
        af[mt][ks] = *(const short8v*)&aS0[LIDX(mt*16 + r16, ks*32 + g8, CF)];
#pragma unroll
    for (int nn = 0; nn < 4; ++nn) {
      int nt = wv*4 + nn;
      int o = nt*16 + r16;
      short8v bfr[4];
#pragma unroll
      for (int ks = 0; ks < 4; ++ks)
        bfr[ks] = *(const short8v*)&WcLp[(size_t)((nt*4 + ks)*64 + lane)*8];
      float bce = bceff[b*CC + o];
#pragma unroll
      for (int mt = 0; mt < 4; ++mt) {
        f32x4 acc = {0.f, 0.f, 0.f, 0.f};
#pragma unroll
        for (int ks = 0; ks < 4; ++ks)
          acc = __builtin_amdgcn_mfma_f32_16x16x32_bf16(af[mt][ks], bfr[ks], acc, 0, 0, 0);
#pragma unroll
        for (int i = 0; i < 4; ++i)
          aS1[LIDX(mt*16 + rowg + i, o, CA)] = f2bf(fmaxf(acc[i] + bce, 0.f));
      }
    }
  }
  __syncthreads();
  // ---- GEMM-d: lf2 = relu(aS1 @ Wd^T + bd) -> aS0 + global local_feat ----
  {
    short8v af[4][8];
#pragma unroll
    for (int mt = 0; mt < 4; ++mt)
#pragma unroll
      for (int ks = 0; ks < 8; ++ks)
        af[mt][ks] = *(const short8v*)&aS1[LIDX(mt*16 + r16, ks*32 + g8, CA)];
#pragma unroll
    for (int nn = 0; nn < 2; ++nn) {
      int nt = wv*2 + nn;
      int o = nt*16 + r16;
      short8v bfr[8];
#pragma unroll
      for (int ks = 0; ks < 8; ++ks)
        bfr[ks] = *(const short8v*)&Wdp[(size_t)((nt*8 + ks)*64 + lane)*8];
      float bdv = bd[o];
#pragma unroll
      for (int mt = 0; mt < 4; ++mt) {
        f32x4 acc = {0.f, 0.f, 0.f, 0.f};
#pragma unroll
        for (int ks = 0; ks < 8; ++ks)
          acc = __builtin_amdgcn_mfma_f32_16x16x32_bf16(af[mt][ks], bfr[ks], acc, 0, 0, 0);
#pragma unroll
        for (int i = 0; i < 4; ++i) {
          float v = fmaxf(acc[i] + bdv, 0.f);
          aS0[LIDX(mt*16 + rowg + i, o, CF)] = f2bf(v);
          out[GF_OFF + ((size_t)(b*CD + o))*NPTS + n0 + mt*16 + rowg + i] = v;
        }
      }
    }
  }
  __syncthreads();
  // ---- GEMM-e: gl1 = relu(aS0 @ We^T + be) -> aS1 ----
  {
    short8v af[4][4];
#pragma unroll
    for (int mt = 0; mt < 4; ++mt)
#pragma unroll
      for (int ks = 0; ks < 4; ++ks)
        af[mt][ks] = *(const short8v*)&aS0[LIDX(mt*16 + r16, ks*32 + g8, CF)];
#pragma unroll
    for (int nn = 0; nn < 4; ++nn) {
      int nt = wv*4 + nn;
      int o = nt*16 + r16;
      short8v bfr[4];
#pragma unroll
      for (int ks = 0; ks < 4; ++ks)
        bfr[ks] = *(const short8v*)&Wep[(size_t)((nt*4 + ks)*64 + lane)*8];
      float bev = be[o];
#pragma unroll
      for (int mt = 0; mt < 4; ++mt) {
        f32x4 acc = {0.f, 0.f, 0.f, 0.f};
#pragma unroll
        for (int ks = 0; ks < 4; ++ks)
          acc = __builtin_amdgcn_mfma_f32_16x16x32_bf16(af[mt][ks], bfr[ks], acc, 0, 0, 0);
#pragma unroll
        for (int i = 0; i < 4; ++i)
          aS1[LIDX(mt*16 + rowg + i, o, CA)] = f2bf(fmaxf(acc[i] + bev, 0.f));
      }
    }
  }
  __syncthreads();
  // ---- GEMM-f: gl2 = gl1 @ Wf^T + bf, relu+max over rows, atomicMax over n ----
  {
    short8v af[4][8];
#pragma unroll
    for (int mt = 0; mt < 4; ++mt)
#pragma unroll
      for (int ks = 0; ks < 8; ++ks)
        af[mt][ks] = *(const short8v*)&aS1[LIDX(mt*16 + r16, ks*32 + g8, CA)];
#pragma unroll
    for (int nn = 0; nn < 8; ++nn) {
      int nt = wv*8 + nn;
      short8v bfr[8];
#pragma unroll
      for (int ks = 0; ks < 8; ++ks)
        bfr[ks] = *(const short8v*)&Wfp[(size_t)((nt*8 + ks)*64 + lane)*8];
      float bfv = bf[nt*16 + r16];
      float am = 0.f;  // relu fold
#pragma unroll
      for (int mt = 0; mt < 4; ++mt) {
        f32x4 acc = {0.f, 0.f, 0.f, 0.f};
#pragma unroll
        for (int ks = 0; ks < 8; ++ks)
          acc = __builtin_amdgcn_mfma_f32_16x16x32_bf16(af[mt][ks], bfr[ks], acc, 0, 0, 0);
#pragma unroll
        for (int i = 0; i < 4; ++i) am = fmaxf(am, acc[i] + bfv);
      }
      am = fmaxf(am, __shfl_xor(am, 16));
      am = fmaxf(am, __shfl_xor(am, 32));
      if (lane < 16) atomicMax(&glmaxU[b*CG + nt*16 + lane], __float_as_uint(am));
    }
  }
}

__global__ void k_final(const unsigned* __restrict__ glmaxU, float* __restrict__ out) {
  int i = blockIdx.x*256 + threadIdx.x;
  if (i < BATCH*CG) out[i] = __uint_as_float(glmaxU[i]);
}

extern "C" void kernel_launch(void* const* d_in, const int* in_sizes, int n_in,
                              void* d_out, int out_size, void* d_ws, size_t ws_size,
                              hipStream_t stream) {
  const float* x   = (const float*)d_in[0];
  const float* f   = (const float*)d_in[1];
  const float* Wit = (const float*)d_in[2];
  const float* bit = (const float*)d_in[3];
  const float* W1  = (const float*)d_in[4];
  const float* gng = (const float*)d_in[5];
  const float* gnb = (const float*)d_in[6];
  const float* Wa  = (const float*)d_in[7];
  const float* ba  = (const float*)d_in[8];
  const float* Wb  = (const float*)d_in[9];
  const float* bb  = (const float*)d_in[10];
  const float* Wc  = (const float*)d_in[11];
  const float* bc  = (const float*)d_in[12];
  const float* Wd  = (const float*)d_in[13];
  const float* bd  = (const float*)d_in[14];
  const float* We  = (const float*)d_in[15];
  const float* be  = (const float*)d_in[16];
  const float* Wf  = (const float*)d_in[17];
  const float* bf  = (const float*)d_in[18];
  float* out = (float*)d_out;

  char* w = (char*)d_ws;
  size_t off = 0;
  auto alloc = [&](size_t bytes) {
    void* p = w + off; off += (bytes + 255) & ~(size_t)255; return p;
  };
  float* h        = (float*)alloc((size_t)BATCH*NPTS*CH*4);
  int*   idx      = (int*)  alloc((size_t)BATCH*NPTS*KNNK*4);
  short* W1p      = (short*)alloc((size_t)CF*CF*2);
  short* Wap      = (short*)alloc((size_t)CA*CF*2);
  short* Wbp      = (short*)alloc((size_t)CB*CA*2);
  short* WcLp     = (short*)alloc((size_t)CC*CF*2);
  short* Wdp      = (short*)alloc((size_t)CD*CC*2);
  short* Wep      = (short*)alloc((size_t)CE*CD*2);
  short* Wfp      = (short*)alloc((size_t)CG*CE*2);
  float* WcT      = (float*)alloc((size_t)CCAT*CC*4);
  float* bceff    = (float*)alloc((size_t)BATCH*CC*4);
  float* partials = (float*)alloc((size_t)(BATCH*NPTS/P)*NGRP*2*4);
  float* stats    = (float*)alloc((size_t)BATCH*NGRP*2*4);
  float* lbase    = (float*)alloc((size_t)BATCH*NPTS*CF*4);
  unsigned* gmaxU  = (unsigned*)alloc((size_t)BATCH*CG*4);
  unsigned* glmaxU = (unsigned*)alloc((size_t)BATCH*CG*4);

  hipMemsetAsync(gmaxU, 0, (size_t)BATCH*CG*4, stream);
  hipMemsetAsync(glmaxU, 0, (size_t)BATCH*CG*4, stream);

  k_pack<<<8,  256, 0, stream>>>(W1, W1p, CF, CF, CF);
  k_pack<<<16, 256, 0, stream>>>(Wa, Wap, CA, CF, CF);
  k_pack<<<64, 256, 0, stream>>>(Wb, Wbp, CB, CA, CA);
  k_pack<<<16, 256, 0, stream>>>(Wc, WcLp, CC, CF, CCAT);
  k_pack<<<16, 256, 0, stream>>>(Wd, Wdp, CD, CC, CC);
  k_pack<<<16, 256, 0, stream>>>(We, Wep, CE, CD, CD);
  k_pack<<<64, 256, 0, stream>>>(Wf, Wfp, CG, CE, CE);
  k_transpose<<<(CC*CCAT+255)/256, 256, 0, stream>>>(Wc, WcT, CC, CCAT);

  k_sq_h<<<(BATCH*NPTS*CH+255)/256, 256, 0, stream>>>(x, f, Wit, bit, h);
  k_knn<<<BATCH*NPTS/4, 256, 0, stream>>>(x, idx);
  k_stats<<<BATCH*NPTS/P, 256, 0, stream>>>(h, idx, W1p, partials);
  k_reduce<<<BATCH*NGRP, 256, 0, stream>>>(partials, stats);
  k_main<<<BATCH*NPTS/P, 256, 0, stream>>>(h, idx, W1p, gng, gnb, stats,
                                           Wap, ba, Wbp, bb, lbase, gmaxU);
  k_gbias<<<BATCH, 256, 0, stream>>>(gmaxU, WcT, bc, bceff);
  k_tail<<<BATCH*NPTS/TM, 256, 0, stream>>>(lbase, bceff, WcLp, Wdp, bd,
                                            Wep, be, Wfp, bf, out, glmaxU);
  k_final<<<(BATCH*CG+255)/256, 256, 0, stream>>>(glmaxU, out);
}